// Round 10
// baseline (77.133 us; speedup 1.0000x reference)
//
#include <hip/hip_runtime.h>

#define N_NODES 50000
#define N_EDGES 800000
#define D_FEAT 128
#define HEADS 8
#define HEAD_DIM 16
#define ELL_CAP 64
#define NBKT 196            // dst>>8 in [0,196)
#define BKT_CAP 5120        // mean 4096, sigma ~64 -> +16 sigma
#define OVF_CAP 65536
#define NB_COLS 144         // 128 h-cols + 8 a_src + 8 a_dst
#define PREP_BLKS 72        // 144*128/256
#define NGEMM ((N_NODES + 63) / 64)   // 782

typedef __attribute__((ext_vector_type(8))) short bf16x8;
typedef __attribute__((ext_vector_type(4))) float f32x4;

static __device__ __forceinline__ ushort f2bf(float f) {
  uint u = __float_as_uint(f);
  u += 0x7fffu + ((u >> 16) & 1u);    // RNE
  return (ushort)(u >> 16);
}
static __device__ __forceinline__ float bf2f_lo(uint u) { return __uint_as_float(u << 16); }
static __device__ __forceinline__ float bf2f_hi(uint u) { return __uint_as_float(u & 0xffff0000u); }

static constexpr size_t alignup(size_t v) { return (v + 255) & ~255ull; }
// ---------------- workspace layout (bytes) ----------------
static constexpr size_t OFF_HB   = 0;                                           // [N,128] bf16
static constexpr size_t OFF_ASRC = alignup(OFF_HB + (size_t)N_NODES * 128 * 2); // [N,8] f32
static constexpr size_t OFF_ADST = alignup(OFF_ASRC + (size_t)N_NODES * 8 * 4); // [N,8] f32
static constexpr size_t OFF_CNT  = alignup(OFF_ADST + (size_t)N_NODES * 8 * 4); // [N] i32
static constexpr size_t OFF_GCNT = alignup(OFF_CNT + (size_t)N_NODES * 4);      // [NBKT] i32
static constexpr size_t OFF_OVFC = OFF_GCNT + (size_t)NBKT * 4;                 // [1] i32 (contig w/ gcnt for memset)
static constexpr size_t OFF_ELL  = alignup(OFF_OVFC + 4);                       // [N*64] u16
static constexpr size_t OFF_BKT  = alignup(OFF_ELL + (size_t)N_NODES * ELL_CAP * 2); // [NBKT*BKT_CAP] u32
static constexpr size_t OFF_OVF  = alignup(OFF_BKT + (size_t)NBKT * BKT_CAP * 4);    // [OVF_CAP] int2
static constexpr size_t OFF_WT   = alignup(OFF_OVF + (size_t)OVF_CAP * 8);      // [144*128] bf16 swizzled

// ---------------- pass 1 + prep: bin edges / build Wt (merged grid) ----------
__global__ __launch_bounds__(256) void k_binprep(const int* __restrict__ src,
                                                 const int* __restrict__ dst,
                                                 int* __restrict__ gcnt,
                                                 uint* __restrict__ bkt,
                                                 int* __restrict__ ovfc,
                                                 int2* __restrict__ ovf,
                                                 const float* __restrict__ W,
                                                 const float* __restrict__ att_src,
                                                 const float* __restrict__ att_dst,
                                                 char* __restrict__ Wt, int E) {
  if (blockIdx.x >= NBKT) {
    int t = (blockIdx.x - NBKT) * 256 + threadIdx.x;   // 0..18431
    int n = t >> 7, k = t & 127;
    float v;
    if (n < 128) {
      v = W[k * 128 + n];
    } else {
      int j = n - 128, jj = j & 7;
      const float* att = (j < 8) ? att_src : att_dst;
      v = 0.f;
#pragma unroll
      for (int c = 0; c < 16; ++c) v += W[k * 128 + jj * 16 + c] * att[jj * 16 + c];
    }
    int off = (n * 256 + k * 2) ^ ((n & 7) << 4);
    *(ushort*)(Wt + off) = f2bf(v);
    return;
  }
  __shared__ int hist[NBKT];
  __shared__ int base[NBKT];
  const int t = threadIdx.x;
  const int e0 = blockIdx.x * 4096;
  for (int i = t; i < NBKT; i += 256) hist[i] = 0;
  __syncthreads();

  uint pk[16];
  int bk[16];
#pragma unroll
  for (int j = 0; j < 4; ++j) {
    int e = e0 + j * 1024 + t * 4;
    if (e < E) {                       // E%4==0: quad fully valid
      int4 d4 = *(const int4*)(dst + e);
      int4 s4 = *(const int4*)(src + e);
      bk[j * 4 + 0] = d4.x >> 8; pk[j * 4 + 0] = ((uint)(d4.x & 255) << 16) | (uint)s4.x;
      bk[j * 4 + 1] = d4.y >> 8; pk[j * 4 + 1] = ((uint)(d4.y & 255) << 16) | (uint)s4.y;
      bk[j * 4 + 2] = d4.z >> 8; pk[j * 4 + 2] = ((uint)(d4.z & 255) << 16) | (uint)s4.z;
      bk[j * 4 + 3] = d4.w >> 8; pk[j * 4 + 3] = ((uint)(d4.w & 255) << 16) | (uint)s4.w;
      atomicAdd(&hist[bk[j * 4 + 0]], 1);
      atomicAdd(&hist[bk[j * 4 + 1]], 1);
      atomicAdd(&hist[bk[j * 4 + 2]], 1);
      atomicAdd(&hist[bk[j * 4 + 3]], 1);
    } else {
      bk[j * 4 + 0] = -1; bk[j * 4 + 1] = -1; bk[j * 4 + 2] = -1; bk[j * 4 + 3] = -1;
      pk[j * 4 + 0] = 0;  pk[j * 4 + 1] = 0;  pk[j * 4 + 2] = 0;  pk[j * 4 + 3] = 0;
    }
  }
  __syncthreads();
  for (int i = t; i < NBKT; i += 256) {
    base[i] = atomicAdd(&gcnt[i], hist[i]);
    hist[i] = 0;
  }
  __syncthreads();
#pragma unroll
  for (int j = 0; j < 16; ++j) {
    if (bk[j] >= 0) {
      int pos = atomicAdd(&hist[bk[j]], 1);
      int gp = base[bk[j]] + pos;
      if (gp < BKT_CAP) {
        bkt[(size_t)bk[j] * BKT_CAP + gp] = pk[j];
      } else {
        int q = atomicAdd(ovfc, 1);
        if (q < OVF_CAP) ovf[q] = make_int2((bk[j] << 8) | (int)(pk[j] >> 16), (int)(pk[j] & 0xffffu));
      }
    }
  }
}

// ---------------- mega-kernel: blocks [0,NGEMM)=MFMA GEMM, rest = ELL build --
__global__ __launch_bounds__(256) void k_gemmbuild(const float* __restrict__ x,
                                                   const char* __restrict__ Wt,
                                                   ushort* __restrict__ hb,
                                                   float* __restrict__ a_src,
                                                   float* __restrict__ a_dst,
                                                   const uint* __restrict__ bkt,
                                                   const int* __restrict__ gcnt,
                                                   int* __restrict__ cnt,
                                                   ushort* __restrict__ ell,
                                                   int* __restrict__ ovfc,
                                                   int2* __restrict__ ovf, int N) {
  __shared__ union SM {
    ushort wl[NB_COLS * 128];                       // 36 KB (gemm branch)
    struct { ushort lell[256 * ELL_CAP]; int lcnt[256]; } b;  // 33 KB (build)
  } sm;
  const int tid = threadIdx.x;

  if (blockIdx.x < NGEMM) {
    // ---------------- GEMM branch ----------------
    const uint4* Wg4 = (const uint4*)Wt;
    uint4* Wl4 = (uint4*)sm.wl;
#pragma unroll
    for (int i = 0; i < 9; ++i) Wl4[tid + i * 256] = Wg4[tid + i * 256];
    __syncthreads();

    const int w = tid >> 6, l = tid & 63;
    const int R = blockIdx.x * 64 + w * 16;
    const int m = l & 15, kg = l >> 4;
    const char* Wlb = (const char*)sm.wl;

    f32x4 acc[9];
#pragma unroll
    for (int j = 0; j < 9; ++j) acc[j] = (f32x4){0.f, 0.f, 0.f, 0.f};

    const int row = R + m;
    const bool valid = row < N;
    const float4* xr = (const float4*)(x + (size_t)(valid ? row : 0) * 128);

#pragma unroll
    for (int kt = 0; kt < 4; ++kt) {
      const int k0 = kt * 32 + kg * 8;
      float4 xa = valid ? xr[k0 >> 2] : make_float4(0.f, 0.f, 0.f, 0.f);
      float4 xb = valid ? xr[(k0 >> 2) + 1] : make_float4(0.f, 0.f, 0.f, 0.f);
      bf16x8 a;
      a[0] = (short)f2bf(xa.x); a[1] = (short)f2bf(xa.y);
      a[2] = (short)f2bf(xa.z); a[3] = (short)f2bf(xa.w);
      a[4] = (short)f2bf(xb.x); a[5] = (short)f2bf(xb.y);
      a[6] = (short)f2bf(xb.z); a[7] = (short)f2bf(xb.w);
#pragma unroll
      for (int j = 0; j < 9; ++j) {
        int n = j * 16 + m;
        int off = (n * 256 + k0 * 2) ^ ((n & 7) << 4);
        bf16x8 b = *(const bf16x8*)(Wlb + off);
        acc[j] = __builtin_amdgcn_mfma_f32_16x16x32_bf16(a, b, acc[j], 0, 0, 0);
      }
    }
    // C layout: col = j*16 + m, row = R + kg*4 + r
#pragma unroll
    for (int j = 0; j < 8; ++j) {
      int col = j * 16 + m;
#pragma unroll
      for (int r = 0; r < 4; ++r) {
        int rr = R + kg * 4 + r;
        if (rr < N) hb[(size_t)rr * 128 + col] = f2bf(acc[j][r]);
      }
    }
#pragma unroll
    for (int r = 0; r < 4; ++r) {
      int rr = R + kg * 4 + r;
      if (rr < N) {
        if (m < 8) a_src[rr * 8 + m] = acc[8][r];
        else       a_dst[rr * 8 + (m - 8)] = acc[8][r];
      }
    }
    return;
  }

  // ---------------- ELL build branch ----------------
  const int b = blockIdx.x - NGEMM;
  const int t = tid;
  sm.b.lcnt[t] = 0;
  __syncthreads();

  const int nb = min(gcnt[b], BKT_CAP);
  for (int i = t; i < nb; i += 256) {
    uint pk = bkt[(size_t)b * BKT_CAP + i];
    int dl = (int)(pk >> 16);
    int pos = atomicAdd(&sm.b.lcnt[dl], 1);
    if (pos < ELL_CAP) {
      sm.b.lell[dl * ELL_CAP + pos] = (ushort)(pk & 0xffffu);
    } else {
      int q = atomicAdd(ovfc, 1);
      if (q < OVF_CAP) ovf[q] = make_int2((b << 8) | dl, (int)(pk & 0xffffu));
    }
  }
  __syncthreads();

  const int n0 = b << 8;
  if (n0 + t < N_NODES) cnt[n0 + t] = sm.b.lcnt[t];
  const uint4* l4 = (const uint4*)sm.b.lell;
  uint4* g4 = (uint4*)(ell + (size_t)n0 * ELL_CAP);
  for (int i = t; i < 2048; i += 256) {       // 256 nodes * 128B = 32KB
    if (n0 + (i >> 3) < N_NODES) g4[i] = l4[i];
  }
}

// ---------------- gather + softmax aggregate + residual + LN ----------------
// Dedup'd softmax: lane l computes p for (edge l&7, head l>>3) -- 1 a_src
// gather + 1 exp per 8-edge block instead of 8 -- then the FMA loop reads
// p(k, hd) via shuffle from lane (hd*8+k).  Same values, same accumulation
// order as before (bit-identical output).
template<bool CLAMP>
static __device__ __forceinline__ void gat_block(const uint* __restrict__ hu,
                                                 const float* __restrict__ a_src,
                                                 const ushort* __restrict__ row,
                                                 int e, int deg, uint hd, uint lane,
                                                 float adst, float& acc0, float& acc1,
                                                 float& den) {
  uint4 qi = *(const uint4*)(row + e);      // 8 u16 indices, wave-uniform 16B
  uint s[8];
  s[0] = qi.x & 0xffffu; s[1] = qi.x >> 16;
  s[2] = qi.y & 0xffffu; s[3] = qi.y >> 16;
  s[4] = qi.z & 0xffffu; s[5] = qi.z >> 16;
  s[6] = qi.w & 0xffffu; s[7] = qi.w >> 16;

  // per-lane p: edge kp = lane&7, head hd = lane>>3 (adst already per-head)
  const uint kp = lane & 7;
  uint w01 = (lane & 2) ? qi.y : qi.x;
  uint w23 = (lane & 2) ? qi.w : qi.z;
  uint word = (lane & 4) ? w23 : w01;
  uint sv = (kp & 1) ? (word >> 16) : (word & 0xffffu);
  float a = a_src[sv * 8u + hd] + adst;
  a = a > 0.f ? a : 0.2f * a;               // LeakyReLU(0.2)
  float pm = __expf(a);
  if (CLAMP && (int)(e + kp) >= deg) pm = 0.f;

  uint u[8];
#pragma unroll
  for (int k = 0; k < 8; ++k) {
    uint sk = s[k];
    if (CLAMP && e + k >= deg) sk = 0;      // safe gather (p already 0)
    u[k] = hu[(sk << 6) | lane];
  }
  const int pbase = (int)(lane & 0x38u);    // hd*8
#pragma unroll
  for (int k = 0; k < 8; ++k) {
    float p = __shfl(pm, pbase | k);        // p(edge k, this lane's head)
    acc0 = fmaf(p, bf2f_lo(u[k]), acc0);
    acc1 = fmaf(p, bf2f_hi(u[k]), acc1);
    den += p;
  }
}

__global__ __launch_bounds__(256) void k_gat(const ushort* __restrict__ hb,
                                             const float* __restrict__ a_src,
                                             const float* __restrict__ a_dst,
                                             const int* __restrict__ cnt,
                                             const ushort* __restrict__ ell,
                                             const int* __restrict__ ovfc,
                                             const int2* __restrict__ ovf,
                                             const float* __restrict__ x,
                                             const float* __restrict__ bias,
                                             const float* __restrict__ gamma,
                                             const float* __restrict__ beta,
                                             float* __restrict__ out, int N) {
  const int wid = threadIdx.x >> 6;
  const uint lane = threadIdx.x & 63;
  const int n = blockIdx.x * 4 + wid;
  if (n >= N) return;
  const uint hd = lane >> 3;
  const float adst = a_dst[n * 8 + hd];
  const int degt = cnt[n];
  const int deg = degt < ELL_CAP ? degt : ELL_CAP;
  const uint* hu = (const uint*)hb;
  const ushort* row = ell + (size_t)n * ELL_CAP;

  float acc0 = 0.f, acc1 = 0.f, den = 0.f;
  const int full = deg & ~7;
  for (int e = 0; e < full; e += 8)
    gat_block<false>(hu, a_src, row, e, deg, hd, lane, adst, acc0, acc1, den);
  if (deg & 7)
    gat_block<true>(hu, a_src, row, full, deg, hd, lane, adst, acc0, acc1, den);

  {
    int novf = *ovfc;                        // ~always 0; one broadcast load
    if (novf > 0) {
      novf = novf < OVF_CAP ? novf : OVF_CAP;
      for (int q = 0; q < novf; ++q) {
        int2 pr = ovf[q];
        if (pr.x == n) {
          uint s = (uint)pr.y;
          float a = a_src[s * 8u + hd] + adst;
          a = a > 0.f ? a : 0.2f * a;
          float p = __expf(a);
          uint u = hu[(s << 6) | lane];
          acc0 = fmaf(p, bf2f_lo(u), acc0);
          acc1 = fmaf(p, bf2f_hi(u), acc1);
          den += p;
        }
      }
    }
  }
  float r = 1.0f / (den + 1e-16f);
  float2 bv = ((const float2*)bias)[lane];
  float2 xv = ((const float2*)x)[(size_t)n * 64 + lane];
  float o0 = fmaf(acc0, r, bv.x + xv.x);
  float o1 = fmaf(acc1, r, bv.y + xv.y);

  float s1 = o0 + o1;
  float s2 = o0 * o0 + o1 * o1;
#pragma unroll
  for (int off = 32; off > 0; off >>= 1) {
    s1 += __shfl_xor(s1, off);
    s2 += __shfl_xor(s2, off);
  }
  float mean = s1 * (1.0f / 128.0f);
  float var = s2 * (1.0f / 128.0f) - mean * mean;
  var = var < 0.f ? 0.f : var;
  float rstd = rsqrtf(var + 1e-5f);
  float2 gv = ((const float2*)gamma)[lane];
  float2 bt = ((const float2*)beta)[lane];
  float2 ov;
  ov.x = (o0 - mean) * rstd * gv.x + bt.x;
  ov.y = (o1 - mean) * rstd * gv.y + bt.y;
  ((float2*)out)[(size_t)n * 64 + lane] = ov;
}

// ---------------- launch ----------------
extern "C" void kernel_launch(void* const* d_in, const int* in_sizes, int n_in,
                              void* d_out, int out_size, void* d_ws, size_t ws_size,
                              hipStream_t stream) {
  const float* x       = (const float*)d_in[0];
  const int*   ei      = (const int*)d_in[1];
  const float* W       = (const float*)d_in[2];
  const float* att_src = (const float*)d_in[3];
  const float* att_dst = (const float*)d_in[4];
  const float* bias    = (const float*)d_in[5];
  const float* gamma   = (const float*)d_in[6];
  const float* beta    = (const float*)d_in[7];
  float* out = (float*)d_out;

  char* ws = (char*)d_ws;
  ushort* hb   = (ushort*)(ws + OFF_HB);
  float* a_src = (float*)(ws + OFF_ASRC);
  float* a_dst = (float*)(ws + OFF_ADST);
  int* cnt   = (int*)(ws + OFF_CNT);
  int* gcnt  = (int*)(ws + OFF_GCNT);
  int* ovfc  = (int*)(ws + OFF_OVFC);
  ushort* ell = (ushort*)(ws + OFF_ELL);
  uint* bkt  = (uint*)(ws + OFF_BKT);
  int2* ovf  = (int2*)(ws + OFF_OVF);
  char* Wt   = ws + OFF_WT;

  const int* srcIdx = ei;
  const int* dstIdx = ei + N_EDGES;

  hipMemsetAsync(ws + OFF_GCNT, 0, (NBKT + 1) * 4, stream);  // gcnt + ovfc
  k_binprep<<<NBKT + PREP_BLKS, 256, 0, stream>>>(srcIdx, dstIdx, gcnt, bkt, ovfc, ovf,
                                                  W, att_src, att_dst, Wt, N_EDGES);
  k_gemmbuild<<<NGEMM + NBKT, 256, 0, stream>>>(x, Wt, hb, a_src, a_dst,
                                                bkt, gcnt, cnt, ell, ovfc, ovf, N_NODES);
  k_gat<<<(N_NODES + 3) / 4, 256, 0, stream>>>(hb, a_src, a_dst, cnt, ell, ovfc, ovf, x, bias, gamma, beta, out, N_NODES);
}

// Round 11
// 76.947 us; speedup vs baseline: 1.0024x; 1.0024x over previous
//
#include <hip/hip_runtime.h>

#define N_NODES 50000
#define N_EDGES 800000
#define D_FEAT 128
#define HEADS 8
#define HEAD_DIM 16
#define ELL_CAP 64
#define NBKT 196            // dst>>8 in [0,196)
#define BKT_CAP 5120        // mean 4096, sigma ~64 -> +16 sigma
#define OVF_CAP 65536
#define NB_COLS 144         // 128 h-cols + 8 a_src + 8 a_dst
#define PREP_BLKS 72        // 144*128/256
#define NGEMM ((N_NODES + 63) / 64)   // 782

typedef __attribute__((ext_vector_type(8))) short bf16x8;
typedef __attribute__((ext_vector_type(4))) float f32x4;

static __device__ __forceinline__ ushort f2bf(float f) {
  uint u = __float_as_uint(f);
  u += 0x7fffu + ((u >> 16) & 1u);    // RNE
  return (ushort)(u >> 16);
}
static __device__ __forceinline__ float bf2f_lo(uint u) { return __uint_as_float(u << 16); }
static __device__ __forceinline__ float bf2f_hi(uint u) { return __uint_as_float(u & 0xffff0000u); }

static constexpr size_t alignup(size_t v) { return (v + 255) & ~255ull; }
// ---------------- workspace layout (bytes) ----------------
static constexpr size_t OFF_HB   = 0;                                           // [N,128] bf16
static constexpr size_t OFF_ASRC = alignup(OFF_HB + (size_t)N_NODES * 128 * 2); // [N,8] f32
static constexpr size_t OFF_ADST = alignup(OFF_ASRC + (size_t)N_NODES * 8 * 4); // [N,8] f32
static constexpr size_t OFF_CNT  = alignup(OFF_ADST + (size_t)N_NODES * 8 * 4); // [N] i32
static constexpr size_t OFF_GCNT = alignup(OFF_CNT + (size_t)N_NODES * 4);      // [NBKT] i32
static constexpr size_t OFF_OVFC = OFF_GCNT + (size_t)NBKT * 4;                 // [1] i32 (contig w/ gcnt for memset)
static constexpr size_t OFF_ELL  = alignup(OFF_OVFC + 4);                       // [N*64] u16
static constexpr size_t OFF_BKT  = alignup(OFF_ELL + (size_t)N_NODES * ELL_CAP * 2); // [NBKT*BKT_CAP] u32
static constexpr size_t OFF_OVF  = alignup(OFF_BKT + (size_t)NBKT * BKT_CAP * 4);    // [OVF_CAP] int2
static constexpr size_t OFF_WT   = alignup(OFF_OVF + (size_t)OVF_CAP * 8);      // [144*128] bf16 swizzled

// ---------------- pass 1 + prep: bin edges / build Wt (merged grid) ----------
__global__ __launch_bounds__(256) void k_binprep(const int* __restrict__ src,
                                                 const int* __restrict__ dst,
                                                 int* __restrict__ gcnt,
                                                 uint* __restrict__ bkt,
                                                 int* __restrict__ ovfc,
                                                 int2* __restrict__ ovf,
                                                 const float* __restrict__ W,
                                                 const float* __restrict__ att_src,
                                                 const float* __restrict__ att_dst,
                                                 char* __restrict__ Wt, int E) {
  if (blockIdx.x >= NBKT) {
    int t = (blockIdx.x - NBKT) * 256 + threadIdx.x;   // 0..18431
    int n = t >> 7, k = t & 127;
    float v;
    if (n < 128) {
      v = W[k * 128 + n];
    } else {
      int j = n - 128, jj = j & 7;
      const float* att = (j < 8) ? att_src : att_dst;
      v = 0.f;
#pragma unroll
      for (int c = 0; c < 16; ++c) v += W[k * 128 + jj * 16 + c] * att[jj * 16 + c];
    }
    int off = (n * 256 + k * 2) ^ ((n & 7) << 4);
    *(ushort*)(Wt + off) = f2bf(v);
    return;
  }
  __shared__ int hist[NBKT];
  __shared__ int base[NBKT];
  const int t = threadIdx.x;
  const int e0 = blockIdx.x * 4096;
  for (int i = t; i < NBKT; i += 256) hist[i] = 0;
  __syncthreads();

  uint pk[16];
  int bk[16];
#pragma unroll
  for (int j = 0; j < 4; ++j) {
    int e = e0 + j * 1024 + t * 4;
    if (e < E) {                       // E%4==0: quad fully valid
      int4 d4 = *(const int4*)(dst + e);
      int4 s4 = *(const int4*)(src + e);
      bk[j * 4 + 0] = d4.x >> 8; pk[j * 4 + 0] = ((uint)(d4.x & 255) << 16) | (uint)s4.x;
      bk[j * 4 + 1] = d4.y >> 8; pk[j * 4 + 1] = ((uint)(d4.y & 255) << 16) | (uint)s4.y;
      bk[j * 4 + 2] = d4.z >> 8; pk[j * 4 + 2] = ((uint)(d4.z & 255) << 16) | (uint)s4.z;
      bk[j * 4 + 3] = d4.w >> 8; pk[j * 4 + 3] = ((uint)(d4.w & 255) << 16) | (uint)s4.w;
      atomicAdd(&hist[bk[j * 4 + 0]], 1);
      atomicAdd(&hist[bk[j * 4 + 1]], 1);
      atomicAdd(&hist[bk[j * 4 + 2]], 1);
      atomicAdd(&hist[bk[j * 4 + 3]], 1);
    } else {
      bk[j * 4 + 0] = -1; bk[j * 4 + 1] = -1; bk[j * 4 + 2] = -1; bk[j * 4 + 3] = -1;
      pk[j * 4 + 0] = 0;  pk[j * 4 + 1] = 0;  pk[j * 4 + 2] = 0;  pk[j * 4 + 3] = 0;
    }
  }
  __syncthreads();
  for (int i = t; i < NBKT; i += 256) {
    base[i] = atomicAdd(&gcnt[i], hist[i]);
    hist[i] = 0;
  }
  __syncthreads();
#pragma unroll
  for (int j = 0; j < 16; ++j) {
    if (bk[j] >= 0) {
      int pos = atomicAdd(&hist[bk[j]], 1);
      int gp = base[bk[j]] + pos;
      if (gp < BKT_CAP) {
        bkt[(size_t)bk[j] * BKT_CAP + gp] = pk[j];
      } else {
        int q = atomicAdd(ovfc, 1);
        if (q < OVF_CAP) ovf[q] = make_int2((bk[j] << 8) | (int)(pk[j] >> 16), (int)(pk[j] & 0xffffu));
      }
    }
  }
}

// ---------------- mega-kernel: blocks [0,NGEMM)=MFMA GEMM, rest = ELL build --
__global__ __launch_bounds__(256) void k_gemmbuild(const float* __restrict__ x,
                                                   const char* __restrict__ Wt,
                                                   ushort* __restrict__ hb,
                                                   float* __restrict__ a_src,
                                                   float* __restrict__ a_dst,
                                                   const uint* __restrict__ bkt,
                                                   const int* __restrict__ gcnt,
                                                   int* __restrict__ cnt,
                                                   ushort* __restrict__ ell,
                                                   int* __restrict__ ovfc,
                                                   int2* __restrict__ ovf, int N) {
  __shared__ union SM {
    ushort wl[NB_COLS * 128];                       // 36 KB (gemm branch)
    struct { ushort lell[256 * ELL_CAP]; int lcnt[256]; } b;  // 33 KB (build)
  } sm;
  const int tid = threadIdx.x;

  if (blockIdx.x < NGEMM) {
    // ---------------- GEMM branch ----------------
    const uint4* Wg4 = (const uint4*)Wt;
    uint4* Wl4 = (uint4*)sm.wl;
#pragma unroll
    for (int i = 0; i < 9; ++i) Wl4[tid + i * 256] = Wg4[tid + i * 256];
    __syncthreads();

    const int w = tid >> 6, l = tid & 63;
    const int R = blockIdx.x * 64 + w * 16;
    const int m = l & 15, kg = l >> 4;
    const char* Wlb = (const char*)sm.wl;

    f32x4 acc[9];
#pragma unroll
    for (int j = 0; j < 9; ++j) acc[j] = (f32x4){0.f, 0.f, 0.f, 0.f};

    const int row = R + m;
    const bool valid = row < N;
    const float4* xr = (const float4*)(x + (size_t)(valid ? row : 0) * 128);

#pragma unroll
    for (int kt = 0; kt < 4; ++kt) {
      const int k0 = kt * 32 + kg * 8;
      float4 xa = valid ? xr[k0 >> 2] : make_float4(0.f, 0.f, 0.f, 0.f);
      float4 xb = valid ? xr[(k0 >> 2) + 1] : make_float4(0.f, 0.f, 0.f, 0.f);
      bf16x8 a;
      a[0] = (short)f2bf(xa.x); a[1] = (short)f2bf(xa.y);
      a[2] = (short)f2bf(xa.z); a[3] = (short)f2bf(xa.w);
      a[4] = (short)f2bf(xb.x); a[5] = (short)f2bf(xb.y);
      a[6] = (short)f2bf(xb.z); a[7] = (short)f2bf(xb.w);
#pragma unroll
      for (int j = 0; j < 9; ++j) {
        int n = j * 16 + m;
        int off = (n * 256 + k0 * 2) ^ ((n & 7) << 4);
        bf16x8 b = *(const bf16x8*)(Wlb + off);
        acc[j] = __builtin_amdgcn_mfma_f32_16x16x32_bf16(a, b, acc[j], 0, 0, 0);
      }
    }
    // C layout: col = j*16 + m, row = R + kg*4 + r
#pragma unroll
    for (int j = 0; j < 8; ++j) {
      int col = j * 16 + m;
#pragma unroll
      for (int r = 0; r < 4; ++r) {
        int rr = R + kg * 4 + r;
        if (rr < N) hb[(size_t)rr * 128 + col] = f2bf(acc[j][r]);
      }
    }
#pragma unroll
    for (int r = 0; r < 4; ++r) {
      int rr = R + kg * 4 + r;
      if (rr < N) {
        if (m < 8) a_src[rr * 8 + m] = acc[8][r];
        else       a_dst[rr * 8 + (m - 8)] = acc[8][r];
      }
    }
    return;
  }

  // ---------------- ELL build branch ----------------
  const int b = blockIdx.x - NGEMM;
  const int t = tid;
  sm.b.lcnt[t] = 0;
  __syncthreads();

  const int nb = min(gcnt[b], BKT_CAP);
  for (int i = t; i < nb; i += 256) {
    uint pk = bkt[(size_t)b * BKT_CAP + i];
    int dl = (int)(pk >> 16);
    int pos = atomicAdd(&sm.b.lcnt[dl], 1);
    if (pos < ELL_CAP) {
      sm.b.lell[dl * ELL_CAP + pos] = (ushort)(pk & 0xffffu);
    } else {
      int q = atomicAdd(ovfc, 1);
      if (q < OVF_CAP) ovf[q] = make_int2((b << 8) | dl, (int)(pk & 0xffffu));
    }
  }
  __syncthreads();

  const int n0 = b << 8;
  if (n0 + t < N_NODES) cnt[n0 + t] = sm.b.lcnt[t];
  const uint4* l4 = (const uint4*)sm.b.lell;
  uint4* g4 = (uint4*)(ell + (size_t)n0 * ELL_CAP);
  for (int i = t; i < 2048; i += 256) {       // 256 nodes * 128B = 32KB
    if (n0 + (i >> 3) < N_NODES) g4[i] = l4[i];
  }
}

// ---------------- gather + softmax aggregate + residual + LN ----------------
// Dedup'd softmax (R10) + 16-edge-wide main blocks for 2x memory-level
// parallelism (18 independent loads in flight). No prefetch double-buffer
// (R8's spill); straight-line wide block, ~50 VGPR.
static __device__ __forceinline__ uint sel_idx(uint4 qi, uint kp) {
  uint w01 = (kp & 2) ? qi.y : qi.x;
  uint w23 = (kp & 2) ? qi.w : qi.z;
  uint word = (kp & 4) ? w23 : w01;
  return (kp & 1) ? (word >> 16) : (word & 0xffffu);
}

// 16 edges, no clamp (deg >= e+16)
static __device__ __forceinline__ void gat_block16(const uint* __restrict__ hu,
                                                   const float* __restrict__ a_src,
                                                   const ushort* __restrict__ row,
                                                   int e, uint hd, uint lane,
                                                   float adst, float& acc0, float& acc1,
                                                   float& den) {
  uint4 qa = *(const uint4*)(row + e);
  uint4 qb = *(const uint4*)(row + e + 8);
  uint s[16];
  s[0] = qa.x & 0xffffu; s[1] = qa.x >> 16; s[2] = qa.y & 0xffffu; s[3] = qa.y >> 16;
  s[4] = qa.z & 0xffffu; s[5] = qa.z >> 16; s[6] = qa.w & 0xffffu; s[7] = qa.w >> 16;
  s[8]  = qb.x & 0xffffu; s[9]  = qb.x >> 16; s[10] = qb.y & 0xffffu; s[11] = qb.y >> 16;
  s[12] = qb.z & 0xffffu; s[13] = qb.z >> 16; s[14] = qb.w & 0xffffu; s[15] = qb.w >> 16;

  const uint kp = lane & 7;
  uint sva = sel_idx(qa, kp);
  uint svb = sel_idx(qb, kp);
  float Aa = a_src[sva * 8u + hd];
  float Ab = a_src[svb * 8u + hd];

  uint u[16];
#pragma unroll
  for (int k = 0; k < 16; ++k) u[k] = hu[(s[k] << 6) | lane];

  float aa = Aa + adst; aa = aa > 0.f ? aa : 0.2f * aa;
  float ab = Ab + adst; ab = ab > 0.f ? ab : 0.2f * ab;
  float pma = __expf(aa);
  float pmb = __expf(ab);

  const int pbase = (int)(lane & 0x38u);    // hd*8
#pragma unroll
  for (int k = 0; k < 8; ++k) {
    float p = __shfl(pma, pbase | k);
    acc0 = fmaf(p, bf2f_lo(u[k]), acc0);
    acc1 = fmaf(p, bf2f_hi(u[k]), acc1);
    den += p;
  }
#pragma unroll
  for (int k = 0; k < 8; ++k) {
    float p = __shfl(pmb, pbase | k);
    acc0 = fmaf(p, bf2f_lo(u[8 + k]), acc0);
    acc1 = fmaf(p, bf2f_hi(u[8 + k]), acc1);
    den += p;
  }
}

template<bool CLAMP>
static __device__ __forceinline__ void gat_block(const uint* __restrict__ hu,
                                                 const float* __restrict__ a_src,
                                                 const ushort* __restrict__ row,
                                                 int e, int deg, uint hd, uint lane,
                                                 float adst, float& acc0, float& acc1,
                                                 float& den) {
  uint4 qi = *(const uint4*)(row + e);      // 8 u16 indices, wave-uniform 16B
  uint s[8];
  s[0] = qi.x & 0xffffu; s[1] = qi.x >> 16;
  s[2] = qi.y & 0xffffu; s[3] = qi.y >> 16;
  s[4] = qi.z & 0xffffu; s[5] = qi.z >> 16;
  s[6] = qi.w & 0xffffu; s[7] = qi.w >> 16;

  const uint kp = lane & 7;
  uint sv = sel_idx(qi, kp);
  float a = a_src[sv * 8u + hd] + adst;
  a = a > 0.f ? a : 0.2f * a;               // LeakyReLU(0.2)
  float pm = __expf(a);
  if (CLAMP && (int)(e + kp) >= deg) pm = 0.f;

  uint u[8];
#pragma unroll
  for (int k = 0; k < 8; ++k) {
    uint sk = s[k];
    if (CLAMP && e + k >= deg) sk = 0;      // safe gather (p already 0)
    u[k] = hu[(sk << 6) | lane];
  }
  const int pbase = (int)(lane & 0x38u);    // hd*8
#pragma unroll
  for (int k = 0; k < 8; ++k) {
    float p = __shfl(pm, pbase | k);        // p(edge k, this lane's head)
    acc0 = fmaf(p, bf2f_lo(u[k]), acc0);
    acc1 = fmaf(p, bf2f_hi(u[k]), acc1);
    den += p;
  }
}

__global__ __launch_bounds__(256) void k_gat(const ushort* __restrict__ hb,
                                             const float* __restrict__ a_src,
                                             const float* __restrict__ a_dst,
                                             const int* __restrict__ cnt,
                                             const ushort* __restrict__ ell,
                                             const int* __restrict__ ovfc,
                                             const int2* __restrict__ ovf,
                                             const float* __restrict__ x,
                                             const float* __restrict__ bias,
                                             const float* __restrict__ gamma,
                                             const float* __restrict__ beta,
                                             float* __restrict__ out, int N) {
  const int wid = threadIdx.x >> 6;
  const uint lane = threadIdx.x & 63;
  const int n = blockIdx.x * 4 + wid;
  if (n >= N) return;
  const uint hd = lane >> 3;
  const float adst = a_dst[n * 8 + hd];
  const int degt = cnt[n];
  const int deg = degt < ELL_CAP ? degt : ELL_CAP;
  const uint* hu = (const uint*)hb;
  const ushort* row = ell + (size_t)n * ELL_CAP;

  float acc0 = 0.f, acc1 = 0.f, den = 0.f;
  int e = 0;
  for (; e + 16 <= deg; e += 16)
    gat_block16(hu, a_src, row, e, hd, lane, adst, acc0, acc1, den);
  if (deg - e >= 8) {
    gat_block<false>(hu, a_src, row, e, deg, hd, lane, adst, acc0, acc1, den);
    e += 8;
  }
  if (e < deg)
    gat_block<true>(hu, a_src, row, e, deg, hd, lane, adst, acc0, acc1, den);

  {
    int novf = *ovfc;                        // ~always 0; one broadcast load
    if (novf > 0) {
      novf = novf < OVF_CAP ? novf : OVF_CAP;
      for (int q = 0; q < novf; ++q) {
        int2 pr = ovf[q];
        if (pr.x == n) {
          uint s = (uint)pr.y;
          float a = a_src[s * 8u + hd] + adst;
          a = a > 0.f ? a : 0.2f * a;
          float p = __expf(a);
          uint u = hu[(s << 6) | lane];
          acc0 = fmaf(p, bf2f_lo(u), acc0);
          acc1 = fmaf(p, bf2f_hi(u), acc1);
          den += p;
        }
      }
    }
  }
  float r = 1.0f / (den + 1e-16f);
  float2 bv = ((const float2*)bias)[lane];
  float2 xv = ((const float2*)x)[(size_t)n * 64 + lane];
  float o0 = fmaf(acc0, r, bv.x + xv.x);
  float o1 = fmaf(acc1, r, bv.y + xv.y);

  float s1 = o0 + o1;
  float s2 = o0 * o0 + o1 * o1;
#pragma unroll
  for (int off = 32; off > 0; off >>= 1) {
    s1 += __shfl_xor(s1, off);
    s2 += __shfl_xor(s2, off);
  }
  float mean = s1 * (1.0f / 128.0f);
  float var = s2 * (1.0f / 128.0f) - mean * mean;
  var = var < 0.f ? 0.f : var;
  float rstd = rsqrtf(var + 1e-5f);
  float2 gv = ((const float2*)gamma)[lane];
  float2 bt = ((const float2*)beta)[lane];
  float2 ov;
  ov.x = (o0 - mean) * rstd * gv.x + bt.x;
  ov.y = (o1 - mean) * rstd * gv.y + bt.y;
  ((float2*)out)[(size_t)n * 64 + lane] = ov;
}

// ---------------- launch ----------------
extern "C" void kernel_launch(void* const* d_in, const int* in_sizes, int n_in,
                              void* d_out, int out_size, void* d_ws, size_t ws_size,
                              hipStream_t stream) {
  const float* x       = (const float*)d_in[0];
  const int*   ei      = (const int*)d_in[1];
  const float* W       = (const float*)d_in[2];
  const float* att_src = (const float*)d_in[3];
  const float* att_dst = (const float*)d_in[4];
  const float* bias    = (const float*)d_in[5];
  const float* gamma   = (const float*)d_in[6];
  const float* beta    = (const float*)d_in[7];
  float* out = (float*)d_out;

  char* ws = (char*)d_ws;
  ushort* hb   = (ushort*)(ws + OFF_HB);
  float* a_src = (float*)(ws + OFF_ASRC);
  float* a_dst = (float*)(ws + OFF_ADST);
  int* cnt   = (int*)(ws + OFF_CNT);
  int* gcnt  = (int*)(ws + OFF_GCNT);
  int* ovfc  = (int*)(ws + OFF_OVFC);
  ushort* ell = (ushort*)(ws + OFF_ELL);
  uint* bkt  = (uint*)(ws + OFF_BKT);
  int2* ovf  = (int2*)(ws + OFF_OVF);
  char* Wt   = ws + OFF_WT;

  const int* srcIdx = ei;
  const int* dstIdx = ei + N_EDGES;

  hipMemsetAsync(ws + OFF_GCNT, 0, (NBKT + 1) * 4, stream);  // gcnt + ovfc
  k_binprep<<<NBKT + PREP_BLKS, 256, 0, stream>>>(srcIdx, dstIdx, gcnt, bkt, ovfc, ovf,
                                                  W, att_src, att_dst, Wt, N_EDGES);
  k_gemmbuild<<<NGEMM + NBKT, 256, 0, stream>>>(x, Wt, hb, a_src, a_dst,
                                                bkt, gcnt, cnt, ell, ovfc, ovf, N_NODES);
  k_gat<<<(N_NODES + 3) / 4, 256, 0, stream>>>(hb, a_src, a_dst, cnt, ell, ovfc, ovf, x, bias, gamma, beta, out, N_NODES);
}

// Round 12
// 69.567 us; speedup vs baseline: 1.1088x; 1.1061x over previous
//
#include <hip/hip_runtime.h>
#include <hip/hip_fp8.h>

#define N_NODES 50000
#define N_EDGES 800000
#define D_FEAT 128
#define HEADS 8
#define HEAD_DIM 16
#define ELL_CAP 64
#define NBKT 196            // dst>>8 in [0,196)
#define BKT_CAP 5120        // mean 4096, sigma ~64 -> +16 sigma
#define OVF_CAP 65536
#define NB_COLS 144         // 128 h-cols + 8 a_src + 8 a_dst
#define PREP_BLKS 72        // 144*128/256
#define NGEMM ((N_NODES + 63) / 64)   // 782

typedef __attribute__((ext_vector_type(8))) short bf16x8;
typedef __attribute__((ext_vector_type(4))) float f32x4;

static __device__ __forceinline__ ushort f2bf(float f) {
  uint u = __float_as_uint(f);
  u += 0x7fffu + ((u >> 16) & 1u);    // RNE
  return (ushort)(u >> 16);
}

// fp8 e4m3 (OCP on gfx950) pack/unpack via HIP types (HW cvt)
static __device__ __forceinline__ ushort pack_fp8x2(float v0, float v1) {
  __hip_fp8x2_e4m3 p(float2{v0, v1});
  return *reinterpret_cast<ushort*>(&p);
}
static __device__ __forceinline__ float2 unpack_fp8x2(ushort raw) {
  __hip_fp8x2_e4m3 p;
  *reinterpret_cast<ushort*>(&p) = raw;
  return static_cast<float2>(p);
}

static constexpr size_t alignup(size_t v) { return (v + 255) & ~255ull; }
// ---------------- workspace layout (bytes) ----------------
static constexpr size_t OFF_HB   = 0;                                           // [N,128] fp8
static constexpr size_t OFF_ASRC = alignup(OFF_HB + (size_t)N_NODES * 128);     // [N,8] f32
static constexpr size_t OFF_ADST = alignup(OFF_ASRC + (size_t)N_NODES * 8 * 4); // [N,8] f32
static constexpr size_t OFF_CNT  = alignup(OFF_ADST + (size_t)N_NODES * 8 * 4); // [N] i32
static constexpr size_t OFF_GCNT = alignup(OFF_CNT + (size_t)N_NODES * 4);      // [NBKT] i32
static constexpr size_t OFF_OVFC = OFF_GCNT + (size_t)NBKT * 4;                 // [1] i32 (contig w/ gcnt for memset)
static constexpr size_t OFF_ELL  = alignup(OFF_OVFC + 4);                       // [N*64] u16
static constexpr size_t OFF_BKT  = alignup(OFF_ELL + (size_t)N_NODES * ELL_CAP * 2); // [NBKT*BKT_CAP] u32
static constexpr size_t OFF_OVF  = alignup(OFF_BKT + (size_t)NBKT * BKT_CAP * 4);    // [OVF_CAP] int2
static constexpr size_t OFF_WT   = alignup(OFF_OVF + (size_t)OVF_CAP * 8);      // [144*128] bf16 swizzled

// ---------------- pass 1 + prep: bin edges / build Wt (merged grid) ----------
__global__ __launch_bounds__(256) void k_binprep(const int* __restrict__ src,
                                                 const int* __restrict__ dst,
                                                 int* __restrict__ gcnt,
                                                 uint* __restrict__ bkt,
                                                 int* __restrict__ ovfc,
                                                 int2* __restrict__ ovf,
                                                 const float* __restrict__ W,
                                                 const float* __restrict__ att_src,
                                                 const float* __restrict__ att_dst,
                                                 char* __restrict__ Wt, int E) {
  if (blockIdx.x >= NBKT) {
    int t = (blockIdx.x - NBKT) * 256 + threadIdx.x;   // 0..18431
    int n = t >> 7, k = t & 127;
    float v;
    if (n < 128) {
      v = W[k * 128 + n];
    } else {
      int j = n - 128, jj = j & 7;
      const float* att = (j < 8) ? att_src : att_dst;
      v = 0.f;
#pragma unroll
      for (int c = 0; c < 16; ++c) v += W[k * 128 + jj * 16 + c] * att[jj * 16 + c];
    }
    int off = (n * 256 + k * 2) ^ ((n & 7) << 4);
    *(ushort*)(Wt + off) = f2bf(v);
    return;
  }
  __shared__ int hist[NBKT];
  __shared__ int base[NBKT];
  const int t = threadIdx.x;
  const int e0 = blockIdx.x * 4096;
  for (int i = t; i < NBKT; i += 256) hist[i] = 0;
  __syncthreads();

  uint pk[16];
  int bk[16];
#pragma unroll
  for (int j = 0; j < 4; ++j) {
    int e = e0 + j * 1024 + t * 4;
    if (e < E) {                       // E%4==0: quad fully valid
      int4 d4 = *(const int4*)(dst + e);
      int4 s4 = *(const int4*)(src + e);
      bk[j * 4 + 0] = d4.x >> 8; pk[j * 4 + 0] = ((uint)(d4.x & 255) << 16) | (uint)s4.x;
      bk[j * 4 + 1] = d4.y >> 8; pk[j * 4 + 1] = ((uint)(d4.y & 255) << 16) | (uint)s4.y;
      bk[j * 4 + 2] = d4.z >> 8; pk[j * 4 + 2] = ((uint)(d4.z & 255) << 16) | (uint)s4.z;
      bk[j * 4 + 3] = d4.w >> 8; pk[j * 4 + 3] = ((uint)(d4.w & 255) << 16) | (uint)s4.w;
      atomicAdd(&hist[bk[j * 4 + 0]], 1);
      atomicAdd(&hist[bk[j * 4 + 1]], 1);
      atomicAdd(&hist[bk[j * 4 + 2]], 1);
      atomicAdd(&hist[bk[j * 4 + 3]], 1);
    } else {
      bk[j * 4 + 0] = -1; bk[j * 4 + 1] = -1; bk[j * 4 + 2] = -1; bk[j * 4 + 3] = -1;
      pk[j * 4 + 0] = 0;  pk[j * 4 + 1] = 0;  pk[j * 4 + 2] = 0;  pk[j * 4 + 3] = 0;
    }
  }
  __syncthreads();
  for (int i = t; i < NBKT; i += 256) {
    base[i] = atomicAdd(&gcnt[i], hist[i]);
    hist[i] = 0;
  }
  __syncthreads();
#pragma unroll
  for (int j = 0; j < 16; ++j) {
    if (bk[j] >= 0) {
      int pos = atomicAdd(&hist[bk[j]], 1);
      int gp = base[bk[j]] + pos;
      if (gp < BKT_CAP) {
        bkt[(size_t)bk[j] * BKT_CAP + gp] = pk[j];
      } else {
        int q = atomicAdd(ovfc, 1);
        if (q < OVF_CAP) ovf[q] = make_int2((bk[j] << 8) | (int)(pk[j] >> 16), (int)(pk[j] & 0xffffu));
      }
    }
  }
}

// ---------------- mega-kernel: blocks [0,NGEMM)=MFMA GEMM, rest = ELL build --
__global__ __launch_bounds__(256) void k_gemmbuild(const float* __restrict__ x,
                                                   const char* __restrict__ Wt,
                                                   ushort* __restrict__ hb8,   // fp8x2 pairs
                                                   float* __restrict__ a_src,
                                                   float* __restrict__ a_dst,
                                                   const uint* __restrict__ bkt,
                                                   const int* __restrict__ gcnt,
                                                   int* __restrict__ cnt,
                                                   ushort* __restrict__ ell,
                                                   int* __restrict__ ovfc,
                                                   int2* __restrict__ ovf, int N) {
  __shared__ union SM {
    ushort wl[NB_COLS * 128];                       // 36 KB (gemm branch)
    struct { ushort lell[256 * ELL_CAP]; int lcnt[256]; } b;  // 33 KB (build)
  } sm;
  const int tid = threadIdx.x;

  if (blockIdx.x < NGEMM) {
    // ---------------- GEMM branch ----------------
    const uint4* Wg4 = (const uint4*)Wt;
    uint4* Wl4 = (uint4*)sm.wl;
#pragma unroll
    for (int i = 0; i < 9; ++i) Wl4[tid + i * 256] = Wg4[tid + i * 256];
    __syncthreads();

    const int w = tid >> 6, l = tid & 63;
    const int R = blockIdx.x * 64 + w * 16;
    const int m = l & 15, kg = l >> 4;
    const char* Wlb = (const char*)sm.wl;

    f32x4 acc[9];
#pragma unroll
    for (int j = 0; j < 9; ++j) acc[j] = (f32x4){0.f, 0.f, 0.f, 0.f};

    const int row = R + m;
    const bool valid = row < N;
    const float4* xr = (const float4*)(x + (size_t)(valid ? row : 0) * 128);

#pragma unroll
    for (int kt = 0; kt < 4; ++kt) {
      const int k0 = kt * 32 + kg * 8;
      float4 xa = valid ? xr[k0 >> 2] : make_float4(0.f, 0.f, 0.f, 0.f);
      float4 xb = valid ? xr[(k0 >> 2) + 1] : make_float4(0.f, 0.f, 0.f, 0.f);
      bf16x8 a;
      a[0] = (short)f2bf(xa.x); a[1] = (short)f2bf(xa.y);
      a[2] = (short)f2bf(xa.z); a[3] = (short)f2bf(xa.w);
      a[4] = (short)f2bf(xb.x); a[5] = (short)f2bf(xb.y);
      a[6] = (short)f2bf(xb.z); a[7] = (short)f2bf(xb.w);
#pragma unroll
      for (int j = 0; j < 9; ++j) {
        int n = j * 16 + m;
        int off = (n * 256 + k0 * 2) ^ ((n & 7) << 4);
        bf16x8 b = *(const bf16x8*)(Wlb + off);
        acc[j] = __builtin_amdgcn_mfma_f32_16x16x32_bf16(a, b, acc[j], 0, 0, 0);
      }
    }
    // C layout: col = j*16 + m, row = R + kg*4 + r.
    // fp8 pack: even-m lane packs (own col, col+1 from lane m^1) -> ushort.
#pragma unroll
    for (int j = 0; j < 8; ++j) {
#pragma unroll
      for (int r = 0; r < 4; ++r) {
        float v0 = acc[j][r];
        float v1 = __shfl_xor(v0, 1);
        int rr = R + kg * 4 + r;
        if (!(m & 1) && rr < N)
          hb8[(size_t)rr * 64 + j * 8 + (m >> 1)] = pack_fp8x2(v0, v1);
      }
    }
#pragma unroll
    for (int r = 0; r < 4; ++r) {
      int rr = R + kg * 4 + r;
      if (rr < N) {
        if (m < 8) a_src[rr * 8 + m] = acc[8][r];
        else       a_dst[rr * 8 + (m - 8)] = acc[8][r];
      }
    }
    return;
  }

  // ---------------- ELL build branch ----------------
  const int b = blockIdx.x - NGEMM;
  const int t = tid;
  sm.b.lcnt[t] = 0;
  __syncthreads();

  const int nb = min(gcnt[b], BKT_CAP);
  for (int i = t; i < nb; i += 256) {
    uint pk = bkt[(size_t)b * BKT_CAP + i];
    int dl = (int)(pk >> 16);
    int pos = atomicAdd(&sm.b.lcnt[dl], 1);
    if (pos < ELL_CAP) {
      sm.b.lell[dl * ELL_CAP + pos] = (ushort)(pk & 0xffffu);
    } else {
      int q = atomicAdd(ovfc, 1);
      if (q < OVF_CAP) ovf[q] = make_int2((b << 8) | dl, (int)(pk & 0xffffu));
    }
  }
  __syncthreads();

  const int n0 = b << 8;
  if (n0 + t < N_NODES) cnt[n0 + t] = sm.b.lcnt[t];
  const uint4* l4 = (const uint4*)sm.b.lell;
  uint4* g4 = (uint4*)(ell + (size_t)n0 * ELL_CAP);
  for (int i = t; i < 2048; i += 256) {       // 256 nodes * 128B = 32KB
    if (n0 + (i >> 3) < N_NODES) g4[i] = l4[i];
  }
}

// ---------------- gather + softmax aggregate + residual + LN ----------------
// Dedup'd softmax (R10); h gathered as fp8 e4m3 (ushort=2 features per lane,
// 128B per edge-row -- half the fabric traffic of bf16).
static __device__ __forceinline__ uint sel_idx(uint4 qi, uint kp) {
  uint w01 = (kp & 2) ? qi.y : qi.x;
  uint w23 = (kp & 2) ? qi.w : qi.z;
  uint word = (kp & 4) ? w23 : w01;
  return (kp & 1) ? (word >> 16) : (word & 0xffffu);
}

template<bool CLAMP>
static __device__ __forceinline__ void gat_block(const ushort* __restrict__ hu8,
                                                 const float* __restrict__ a_src,
                                                 const ushort* __restrict__ row,
                                                 int e, int deg, uint hd, uint lane,
                                                 float adst, float& acc0, float& acc1,
                                                 float& den) {
  uint4 qi = *(const uint4*)(row + e);      // 8 u16 indices, wave-uniform 16B
  uint s[8];
  s[0] = qi.x & 0xffffu; s[1] = qi.x >> 16;
  s[2] = qi.y & 0xffffu; s[3] = qi.y >> 16;
  s[4] = qi.z & 0xffffu; s[5] = qi.z >> 16;
  s[6] = qi.w & 0xffffu; s[7] = qi.w >> 16;

  const uint kp = lane & 7;
  uint sv = sel_idx(qi, kp);
  float a = a_src[sv * 8u + hd] + adst;
  a = a > 0.f ? a : 0.2f * a;               // LeakyReLU(0.2)
  float pm = __expf(a);
  if (CLAMP && (int)(e + kp) >= deg) pm = 0.f;

  ushort u[8];
#pragma unroll
  for (int k = 0; k < 8; ++k) {
    uint sk = s[k];
    if (CLAMP && e + k >= deg) sk = 0;      // safe gather (p already 0)
    u[k] = hu8[(sk << 6) | lane];
  }
  const int pbase = (int)(lane & 0x38u);    // hd*8
#pragma unroll
  for (int k = 0; k < 8; ++k) {
    float p = __shfl(pm, pbase | k);        // p(edge k, this lane's head)
    float2 hv = unpack_fp8x2(u[k]);
    acc0 = fmaf(p, hv.x, acc0);
    acc1 = fmaf(p, hv.y, acc1);
    den += p;
  }
}

__global__ __launch_bounds__(256) void k_gat(const ushort* __restrict__ hb8,
                                             const float* __restrict__ a_src,
                                             const float* __restrict__ a_dst,
                                             const int* __restrict__ cnt,
                                             const ushort* __restrict__ ell,
                                             const int* __restrict__ ovfc,
                                             const int2* __restrict__ ovf,
                                             const float* __restrict__ x,
                                             const float* __restrict__ bias,
                                             const float* __restrict__ gamma,
                                             const float* __restrict__ beta,
                                             float* __restrict__ out, int N) {
  const int wid = threadIdx.x >> 6;
  const uint lane = threadIdx.x & 63;
  const int n = blockIdx.x * 4 + wid;
  if (n >= N) return;
  const uint hd = lane >> 3;
  const float adst = a_dst[n * 8 + hd];
  const int degt = cnt[n];
  const int deg = degt < ELL_CAP ? degt : ELL_CAP;
  const ushort* row = ell + (size_t)n * ELL_CAP;

  float acc0 = 0.f, acc1 = 0.f, den = 0.f;
  const int full = deg & ~7;
  for (int e = 0; e < full; e += 8)
    gat_block<false>(hb8, a_src, row, e, deg, hd, lane, adst, acc0, acc1, den);
  if (deg & 7)
    gat_block<true>(hb8, a_src, row, full, deg, hd, lane, adst, acc0, acc1, den);

  {
    int novf = *ovfc;                        // ~always 0; one broadcast load
    if (novf > 0) {
      novf = novf < OVF_CAP ? novf : OVF_CAP;
      for (int q = 0; q < novf; ++q) {
        int2 pr = ovf[q];
        if (pr.x == n) {
          uint s = (uint)pr.y;
          float a = a_src[s * 8u + hd] + adst;
          a = a > 0.f ? a : 0.2f * a;
          float p = __expf(a);
          float2 hv = unpack_fp8x2(hb8[(s << 6) | lane]);
          acc0 = fmaf(p, hv.x, acc0);
          acc1 = fmaf(p, hv.y, acc1);
          den += p;
        }
      }
    }
  }
  float r = 1.0f / (den + 1e-16f);
  float2 bv = ((const float2*)bias)[lane];
  float2 xv = ((const float2*)x)[(size_t)n * 64 + lane];
  float o0 = fmaf(acc0, r, bv.x + xv.x);
  float o1 = fmaf(acc1, r, bv.y + xv.y);

  float s1 = o0 + o1;
  float s2 = o0 * o0 + o1 * o1;
#pragma unroll
  for (int off = 32; off > 0; off >>= 1) {
    s1 += __shfl_xor(s1, off);
    s2 += __shfl_xor(s2, off);
  }
  float mean = s1 * (1.0f / 128.0f);
  float var = s2 * (1.0f / 128.0f) - mean * mean;
  var = var < 0.f ? 0.f : var;
  float rstd = rsqrtf(var + 1e-5f);
  float2 gv = ((const float2*)gamma)[lane];
  float2 bt = ((const float2*)beta)[lane];
  float2 ov;
  ov.x = (o0 - mean) * rstd * gv.x + bt.x;
  ov.y = (o1 - mean) * rstd * gv.y + bt.y;
  ((float2*)out)[(size_t)n * 64 + lane] = ov;
}

// ---------------- launch ----------------
extern "C" void kernel_launch(void* const* d_in, const int* in_sizes, int n_in,
                              void* d_out, int out_size, void* d_ws, size_t ws_size,
                              hipStream_t stream) {
  const float* x       = (const float*)d_in[0];
  const int*   ei      = (const int*)d_in[1];
  const float* W       = (const float*)d_in[2];
  const float* att_src = (const float*)d_in[3];
  const float* att_dst = (const float*)d_in[4];
  const float* bias    = (const float*)d_in[5];
  const float* gamma   = (const float*)d_in[6];
  const float* beta    = (const float*)d_in[7];
  float* out = (float*)d_out;

  char* ws = (char*)d_ws;
  ushort* hb8  = (ushort*)(ws + OFF_HB);
  float* a_src = (float*)(ws + OFF_ASRC);
  float* a_dst = (float*)(ws + OFF_ADST);
  int* cnt   = (int*)(ws + OFF_CNT);
  int* gcnt  = (int*)(ws + OFF_GCNT);
  int* ovfc  = (int*)(ws + OFF_OVFC);
  ushort* ell = (ushort*)(ws + OFF_ELL);
  uint* bkt  = (uint*)(ws + OFF_BKT);
  int2* ovf  = (int2*)(ws + OFF_OVF);
  char* Wt   = ws + OFF_WT;

  const int* srcIdx = ei;
  const int* dstIdx = ei + N_EDGES;

  hipMemsetAsync(ws + OFF_GCNT, 0, (NBKT + 1) * 4, stream);  // gcnt + ovfc
  k_binprep<<<NBKT + PREP_BLKS, 256, 0, stream>>>(srcIdx, dstIdx, gcnt, bkt, ovfc, ovf,
                                                  W, att_src, att_dst, Wt, N_EDGES);
  k_gemmbuild<<<NGEMM + NBKT, 256, 0, stream>>>(x, Wt, hb8, a_src, a_dst,
                                                bkt, gcnt, cnt, ell, ovfc, ovf, N_NODES);
  k_gat<<<(N_NODES + 3) / 4, 256, 0, stream>>>(hb8, a_src, a_dst, cnt, ell, ovfc, ovf, x, bias, gamma, beta, out, N_NODES);
}

// Round 13
// 67.018 us; speedup vs baseline: 1.1509x; 1.0380x over previous
//
#include <hip/hip_runtime.h>
#include <hip/hip_fp8.h>

#define N_NODES 50000
#define N_EDGES 800000
#define D_FEAT 128
#define HEADS 8
#define HEAD_DIM 16
#define ELL_CAP 64
#define NBKT 196            // dst>>8 in [0,196)
#define BKT_CAP 5120        // mean 4096, sigma ~64 -> +16 sigma
#define OVF_CAP 65536
#define NB_COLS 144         // 128 h-cols + 8 a_src + 8 a_dst
#define PREP_BLKS 72        // 144*128/256
#define NGEMM ((N_NODES + 63) / 64)   // 782

typedef __attribute__((ext_vector_type(8))) short bf16x8;
typedef __attribute__((ext_vector_type(4))) float f32x4;

static __device__ __forceinline__ ushort f2bf(float f) {
  uint u = __float_as_uint(f);
  u += 0x7fffu + ((u >> 16) & 1u);    // RNE
  return (ushort)(u >> 16);
}

// fp8 e4m3 (OCP on gfx950) pack/unpack via HIP types (HW cvt)
static __device__ __forceinline__ ushort pack_fp8x2(float v0, float v1) {
  __hip_fp8x2_e4m3 p(float2{v0, v1});
  return *reinterpret_cast<ushort*>(&p);
}
static __device__ __forceinline__ float2 unpack_fp8x2(ushort raw) {
  __hip_fp8x2_e4m3 p;
  *reinterpret_cast<ushort*>(&p) = raw;
  return static_cast<float2>(p);
}

static constexpr size_t alignup(size_t v) { return (v + 255) & ~255ull; }
// ---------------- workspace layout (bytes) ----------------
static constexpr size_t OFF_HB   = 0;                                           // [N,128] fp8
static constexpr size_t OFF_ASRC = alignup(OFF_HB + (size_t)N_NODES * 128);     // [N,8] f32
static constexpr size_t OFF_ADST = alignup(OFF_ASRC + (size_t)N_NODES * 8 * 4); // [N,8] f32
static constexpr size_t OFF_CNT  = alignup(OFF_ADST + (size_t)N_NODES * 8 * 4); // [N] i32
static constexpr size_t OFF_GCNT = alignup(OFF_CNT + (size_t)N_NODES * 4);      // [NBKT] i32
static constexpr size_t OFF_OVFC = OFF_GCNT + (size_t)NBKT * 4;                 // [1] i32 (contig w/ gcnt for memset)
static constexpr size_t OFF_ELL  = alignup(OFF_OVFC + 4);                       // [N*64] u16
static constexpr size_t OFF_BKT  = alignup(OFF_ELL + (size_t)N_NODES * ELL_CAP * 2); // [NBKT*BKT_CAP] u32
static constexpr size_t OFF_OVF  = alignup(OFF_BKT + (size_t)NBKT * BKT_CAP * 4);    // [OVF_CAP] int2
static constexpr size_t OFF_WT   = alignup(OFF_OVF + (size_t)OVF_CAP * 8);      // [144*128] bf16 swizzled

// ---------------- pass 1 + prep: bin edges / build Wt (merged grid) ----------
__global__ __launch_bounds__(256) void k_binprep(const int* __restrict__ src,
                                                 const int* __restrict__ dst,
                                                 int* __restrict__ gcnt,
                                                 uint* __restrict__ bkt,
                                                 int* __restrict__ ovfc,
                                                 int2* __restrict__ ovf,
                                                 const float* __restrict__ W,
                                                 const float* __restrict__ att_src,
                                                 const float* __restrict__ att_dst,
                                                 char* __restrict__ Wt, int E) {
  if (blockIdx.x >= NBKT) {
    int t = (blockIdx.x - NBKT) * 256 + threadIdx.x;   // 0..18431
    int n = t >> 7, k = t & 127;
    float v;
    if (n < 128) {
      v = W[k * 128 + n];
    } else {
      int j = n - 128, jj = j & 7;
      const float* att = (j < 8) ? att_src : att_dst;
      v = 0.f;
#pragma unroll
      for (int c = 0; c < 16; ++c) v += W[k * 128 + jj * 16 + c] * att[jj * 16 + c];
    }
    int off = (n * 256 + k * 2) ^ ((n & 7) << 4);
    *(ushort*)(Wt + off) = f2bf(v);
    return;
  }
  __shared__ int hist[NBKT];
  __shared__ int base[NBKT];
  const int t = threadIdx.x;
  const int e0 = blockIdx.x * 4096;
  for (int i = t; i < NBKT; i += 256) hist[i] = 0;
  __syncthreads();

  uint pk[16];
  int bk[16];
#pragma unroll
  for (int j = 0; j < 4; ++j) {
    int e = e0 + j * 1024 + t * 4;
    if (e < E) {                       // E%4==0: quad fully valid
      int4 d4 = *(const int4*)(dst + e);
      int4 s4 = *(const int4*)(src + e);
      bk[j * 4 + 0] = d4.x >> 8; pk[j * 4 + 0] = ((uint)(d4.x & 255) << 16) | (uint)s4.x;
      bk[j * 4 + 1] = d4.y >> 8; pk[j * 4 + 1] = ((uint)(d4.y & 255) << 16) | (uint)s4.y;
      bk[j * 4 + 2] = d4.z >> 8; pk[j * 4 + 2] = ((uint)(d4.z & 255) << 16) | (uint)s4.z;
      bk[j * 4 + 3] = d4.w >> 8; pk[j * 4 + 3] = ((uint)(d4.w & 255) << 16) | (uint)s4.w;
      atomicAdd(&hist[bk[j * 4 + 0]], 1);
      atomicAdd(&hist[bk[j * 4 + 1]], 1);
      atomicAdd(&hist[bk[j * 4 + 2]], 1);
      atomicAdd(&hist[bk[j * 4 + 3]], 1);
    } else {
      bk[j * 4 + 0] = -1; bk[j * 4 + 1] = -1; bk[j * 4 + 2] = -1; bk[j * 4 + 3] = -1;
      pk[j * 4 + 0] = 0;  pk[j * 4 + 1] = 0;  pk[j * 4 + 2] = 0;  pk[j * 4 + 3] = 0;
    }
  }
  __syncthreads();
  for (int i = t; i < NBKT; i += 256) {
    base[i] = atomicAdd(&gcnt[i], hist[i]);
    hist[i] = 0;
  }
  __syncthreads();
#pragma unroll
  for (int j = 0; j < 16; ++j) {
    if (bk[j] >= 0) {
      int pos = atomicAdd(&hist[bk[j]], 1);
      int gp = base[bk[j]] + pos;
      if (gp < BKT_CAP) {
        bkt[(size_t)bk[j] * BKT_CAP + gp] = pk[j];
      } else {
        int q = atomicAdd(ovfc, 1);
        if (q < OVF_CAP) ovf[q] = make_int2((bk[j] << 8) | (int)(pk[j] >> 16), (int)(pk[j] & 0xffffu));
      }
    }
  }
}

// ---------------- mega-kernel: blocks [0,NGEMM)=MFMA GEMM, rest = ELL build --
__global__ __launch_bounds__(256) void k_gemmbuild(const float* __restrict__ x,
                                                   const char* __restrict__ Wt,
                                                   ushort* __restrict__ hb8,   // fp8x2 pairs
                                                   float* __restrict__ a_src,
                                                   float* __restrict__ a_dst,
                                                   const uint* __restrict__ bkt,
                                                   const int* __restrict__ gcnt,
                                                   int* __restrict__ cnt,
                                                   ushort* __restrict__ ell,
                                                   int* __restrict__ ovfc,
                                                   int2* __restrict__ ovf, int N) {
  __shared__ union SM {
    ushort wl[NB_COLS * 128];                       // 36 KB (gemm branch)
    struct { ushort lell[256 * ELL_CAP]; int lcnt[256]; } b;  // 33 KB (build)
  } sm;
  const int tid = threadIdx.x;

  if (blockIdx.x < NGEMM) {
    // ---------------- GEMM branch ----------------
    const uint4* Wg4 = (const uint4*)Wt;
    uint4* Wl4 = (uint4*)sm.wl;
#pragma unroll
    for (int i = 0; i < 9; ++i) Wl4[tid + i * 256] = Wg4[tid + i * 256];
    __syncthreads();

    const int w = tid >> 6, l = tid & 63;
    const int R = blockIdx.x * 64 + w * 16;
    const int m = l & 15, kg = l >> 4;
    const char* Wlb = (const char*)sm.wl;

    f32x4 acc[9];
#pragma unroll
    for (int j = 0; j < 9; ++j) acc[j] = (f32x4){0.f, 0.f, 0.f, 0.f};

    const int row = R + m;
    const bool valid = row < N;
    const float4* xr = (const float4*)(x + (size_t)(valid ? row : 0) * 128);

#pragma unroll
    for (int kt = 0; kt < 4; ++kt) {
      const int k0 = kt * 32 + kg * 8;
      float4 xa = valid ? xr[k0 >> 2] : make_float4(0.f, 0.f, 0.f, 0.f);
      float4 xb = valid ? xr[(k0 >> 2) + 1] : make_float4(0.f, 0.f, 0.f, 0.f);
      bf16x8 a;
      a[0] = (short)f2bf(xa.x); a[1] = (short)f2bf(xa.y);
      a[2] = (short)f2bf(xa.z); a[3] = (short)f2bf(xa.w);
      a[4] = (short)f2bf(xb.x); a[5] = (short)f2bf(xb.y);
      a[6] = (short)f2bf(xb.z); a[7] = (short)f2bf(xb.w);
#pragma unroll
      for (int j = 0; j < 9; ++j) {
        int n = j * 16 + m;
        int off = (n * 256 + k0 * 2) ^ ((n & 7) << 4);
        bf16x8 b = *(const bf16x8*)(Wlb + off);
        acc[j] = __builtin_amdgcn_mfma_f32_16x16x32_bf16(a, b, acc[j], 0, 0, 0);
      }
    }
    // C layout: col = j*16 + m, row = R + kg*4 + r.
    // fp8 pack: even-m lane packs (own col, col+1 from lane m^1) -> ushort.
#pragma unroll
    for (int j = 0; j < 8; ++j) {
#pragma unroll
      for (int r = 0; r < 4; ++r) {
        float v0 = acc[j][r];
        float v1 = __shfl_xor(v0, 1);
        int rr = R + kg * 4 + r;
        if (!(m & 1) && rr < N)
          hb8[(size_t)rr * 64 + j * 8 + (m >> 1)] = pack_fp8x2(v0, v1);
      }
    }
#pragma unroll
    for (int r = 0; r < 4; ++r) {
      int rr = R + kg * 4 + r;
      if (rr < N) {
        if (m < 8) a_src[rr * 8 + m] = acc[8][r];
        else       a_dst[rr * 8 + (m - 8)] = acc[8][r];
      }
    }
    return;
  }

  // ---------------- ELL build branch ----------------
  const int b = blockIdx.x - NGEMM;
  const int t = tid;
  sm.b.lcnt[t] = 0;
  __syncthreads();

  const int nb = min(gcnt[b], BKT_CAP);
  for (int i = t; i < nb; i += 256) {
    uint pk = bkt[(size_t)b * BKT_CAP + i];
    int dl = (int)(pk >> 16);
    int pos = atomicAdd(&sm.b.lcnt[dl], 1);
    if (pos < ELL_CAP) {
      sm.b.lell[dl * ELL_CAP + pos] = (ushort)(pk & 0xffffu);
    } else {
      int q = atomicAdd(ovfc, 1);
      if (q < OVF_CAP) ovf[q] = make_int2((b << 8) | dl, (int)(pk & 0xffffu));
    }
  }
  __syncthreads();

  const int n0 = b << 8;
  if (n0 + t < N_NODES) cnt[n0 + t] = sm.b.lcnt[t];
  const uint4* l4 = (const uint4*)sm.b.lell;
  uint4* g4 = (uint4*)(ell + (size_t)n0 * ELL_CAP);
  for (int i = t; i < 2048; i += 256) {       // 256 nodes * 128B = 32KB
    if (n0 + (i >> 3) < N_NODES) g4[i] = l4[i];
  }
}

// ---------------- gather + softmax aggregate + residual + LN ----------------
// Dedup'd softmax (R10) + fp8 h-table (R12) + 16-edge-wide main blocks for
// 2x memory-level parallelism (~19 independent requests in flight).
static __device__ __forceinline__ uint sel_idx(uint4 qi, uint kp) {
  uint w01 = (kp & 2) ? qi.y : qi.x;
  uint w23 = (kp & 2) ? qi.w : qi.z;
  uint word = (kp & 4) ? w23 : w01;
  return (kp & 1) ? (word >> 16) : (word & 0xffffu);
}

// 16 edges, no clamp (deg >= e+16)
static __device__ __forceinline__ void gat_block16(const ushort* __restrict__ hu8,
                                                   const float* __restrict__ a_src,
                                                   const ushort* __restrict__ row,
                                                   int e, uint hd, uint lane,
                                                   float adst, float& acc0, float& acc1,
                                                   float& den) {
  uint4 qa = *(const uint4*)(row + e);
  uint4 qb = *(const uint4*)(row + e + 8);
  uint s[16];
  s[0] = qa.x & 0xffffu; s[1] = qa.x >> 16; s[2] = qa.y & 0xffffu; s[3] = qa.y >> 16;
  s[4] = qa.z & 0xffffu; s[5] = qa.z >> 16; s[6] = qa.w & 0xffffu; s[7] = qa.w >> 16;
  s[8]  = qb.x & 0xffffu; s[9]  = qb.x >> 16; s[10] = qb.y & 0xffffu; s[11] = qb.y >> 16;
  s[12] = qb.z & 0xffffu; s[13] = qb.z >> 16; s[14] = qb.w & 0xffffu; s[15] = qb.w >> 16;

  const uint kp = lane & 7;
  uint sva = sel_idx(qa, kp);
  uint svb = sel_idx(qb, kp);
  float Aa = a_src[sva * 8u + hd];
  float Ab = a_src[svb * 8u + hd];

  ushort u[16];
#pragma unroll
  for (int k = 0; k < 16; ++k) u[k] = hu8[(s[k] << 6) | lane];

  float aa = Aa + adst; aa = aa > 0.f ? aa : 0.2f * aa;
  float ab = Ab + adst; ab = ab > 0.f ? ab : 0.2f * ab;
  float pma = __expf(aa);
  float pmb = __expf(ab);

  const int pbase = (int)(lane & 0x38u);    // hd*8
#pragma unroll
  for (int k = 0; k < 8; ++k) {
    float p = __shfl(pma, pbase | k);
    float2 hv = unpack_fp8x2(u[k]);
    acc0 = fmaf(p, hv.x, acc0);
    acc1 = fmaf(p, hv.y, acc1);
    den += p;
  }
#pragma unroll
  for (int k = 0; k < 8; ++k) {
    float p = __shfl(pmb, pbase | k);
    float2 hv = unpack_fp8x2(u[8 + k]);
    acc0 = fmaf(p, hv.x, acc0);
    acc1 = fmaf(p, hv.y, acc1);
    den += p;
  }
}

template<bool CLAMP>
static __device__ __forceinline__ void gat_block(const ushort* __restrict__ hu8,
                                                 const float* __restrict__ a_src,
                                                 const ushort* __restrict__ row,
                                                 int e, int deg, uint hd, uint lane,
                                                 float adst, float& acc0, float& acc1,
                                                 float& den) {
  uint4 qi = *(const uint4*)(row + e);      // 8 u16 indices, wave-uniform 16B
  uint s[8];
  s[0] = qi.x & 0xffffu; s[1] = qi.x >> 16;
  s[2] = qi.y & 0xffffu; s[3] = qi.y >> 16;
  s[4] = qi.z & 0xffffu; s[5] = qi.z >> 16;
  s[6] = qi.w & 0xffffu; s[7] = qi.w >> 16;

  const uint kp = lane & 7;
  uint sv = sel_idx(qi, kp);
  float a = a_src[sv * 8u + hd] + adst;
  a = a > 0.f ? a : 0.2f * a;               // LeakyReLU(0.2)
  float pm = __expf(a);
  if (CLAMP && (int)(e + kp) >= deg) pm = 0.f;

  ushort u[8];
#pragma unroll
  for (int k = 0; k < 8; ++k) {
    uint sk = s[k];
    if (CLAMP && e + k >= deg) sk = 0;      // safe gather (p already 0)
    u[k] = hu8[(sk << 6) | lane];
  }
  const int pbase = (int)(lane & 0x38u);    // hd*8
#pragma unroll
  for (int k = 0; k < 8; ++k) {
    float p = __shfl(pm, pbase | k);        // p(edge k, this lane's head)
    float2 hv = unpack_fp8x2(u[k]);
    acc0 = fmaf(p, hv.x, acc0);
    acc1 = fmaf(p, hv.y, acc1);
    den += p;
  }
}

__global__ __launch_bounds__(256) void k_gat(const ushort* __restrict__ hb8,
                                             const float* __restrict__ a_src,
                                             const float* __restrict__ a_dst,
                                             const int* __restrict__ cnt,
                                             const ushort* __restrict__ ell,
                                             const int* __restrict__ ovfc,
                                             const int2* __restrict__ ovf,
                                             const float* __restrict__ x,
                                             const float* __restrict__ bias,
                                             const float* __restrict__ gamma,
                                             const float* __restrict__ beta,
                                             float* __restrict__ out, int N) {
  const int wid = threadIdx.x >> 6;
  const uint lane = threadIdx.x & 63;
  const int n = blockIdx.x * 4 + wid;
  if (n >= N) return;
  const uint hd = lane >> 3;
  const float adst = a_dst[n * 8 + hd];
  const int degt = cnt[n];
  const int deg = degt < ELL_CAP ? degt : ELL_CAP;
  const ushort* row = ell + (size_t)n * ELL_CAP;

  float acc0 = 0.f, acc1 = 0.f, den = 0.f;
  int e = 0;
  for (; e + 16 <= deg; e += 16)
    gat_block16(hb8, a_src, row, e, hd, lane, adst, acc0, acc1, den);
  if (deg - e >= 8) {
    gat_block<false>(hb8, a_src, row, e, deg, hd, lane, adst, acc0, acc1, den);
    e += 8;
  }
  if (e < deg)
    gat_block<true>(hb8, a_src, row, e, deg, hd, lane, adst, acc0, acc1, den);

  {
    int novf = *ovfc;                        // ~always 0; one broadcast load
    if (novf > 0) {
      novf = novf < OVF_CAP ? novf : OVF_CAP;
      for (int q = 0; q < novf; ++q) {
        int2 pr = ovf[q];
        if (pr.x == n) {
          uint s = (uint)pr.y;
          float a = a_src[s * 8u + hd] + adst;
          a = a > 0.f ? a : 0.2f * a;
          float p = __expf(a);
          float2 hv = unpack_fp8x2(hb8[(s << 6) | lane]);
          acc0 = fmaf(p, hv.x, acc0);
          acc1 = fmaf(p, hv.y, acc1);
          den += p;
        }
      }
    }
  }
  float r = 1.0f / (den + 1e-16f);
  float2 bv = ((const float2*)bias)[lane];
  float2 xv = ((const float2*)x)[(size_t)n * 64 + lane];
  float o0 = fmaf(acc0, r, bv.x + xv.x);
  float o1 = fmaf(acc1, r, bv.y + xv.y);

  float s1 = o0 + o1;
  float s2 = o0 * o0 + o1 * o1;
#pragma unroll
  for (int off = 32; off > 0; off >>= 1) {
    s1 += __shfl_xor(s1, off);
    s2 += __shfl_xor(s2, off);
  }
  float mean = s1 * (1.0f / 128.0f);
  float var = s2 * (1.0f / 128.0f) - mean * mean;
  var = var < 0.f ? 0.f : var;
  float rstd = rsqrtf(var + 1e-5f);
  float2 gv = ((const float2*)gamma)[lane];
  float2 bt = ((const float2*)beta)[lane];
  float2 ov;
  ov.x = (o0 - mean) * rstd * gv.x + bt.x;
  ov.y = (o1 - mean) * rstd * gv.y + bt.y;
  ((float2*)out)[(size_t)n * 64 + lane] = ov;
}

// ---------------- launch ----------------
extern "C" void kernel_launch(void* const* d_in, const int* in_sizes, int n_in,
                              void* d_out, int out_size, void* d_ws, size_t ws_size,
                              hipStream_t stream) {
  const float* x       = (const float*)d_in[0];
  const int*   ei      = (const int*)d_in[1];
  const float* W       = (const float*)d_in[2];
  const float* att_src = (const float*)d_in[3];
  const float* att_dst = (const float*)d_in[4];
  const float* bias    = (const float*)d_in[5];
  const float* gamma   = (const float*)d_in[6];
  const float* beta    = (const float*)d_in[7];
  float* out = (float*)d_out;

  char* ws = (char*)d_ws;
  ushort* hb8  = (ushort*)(ws + OFF_HB);
  float* a_src = (float*)(ws + OFF_ASRC);
  float* a_dst = (float*)(ws + OFF_ADST);
  int* cnt   = (int*)(ws + OFF_CNT);
  int* gcnt  = (int*)(ws + OFF_GCNT);
  int* ovfc  = (int*)(ws + OFF_OVFC);
  ushort* ell = (ushort*)(ws + OFF_ELL);
  uint* bkt  = (uint*)(ws + OFF_BKT);
  int2* ovf  = (int2*)(ws + OFF_OVF);
  char* Wt   = ws + OFF_WT;

  const int* srcIdx = ei;
  const int* dstIdx = ei + N_EDGES;

  hipMemsetAsync(ws + OFF_GCNT, 0, (NBKT + 1) * 4, stream);  // gcnt + ovfc
  k_binprep<<<NBKT + PREP_BLKS, 256, 0, stream>>>(srcIdx, dstIdx, gcnt, bkt, ovfc, ovf,
                                                  W, att_src, att_dst, Wt, N_EDGES);
  k_gemmbuild<<<NGEMM + NBKT, 256, 0, stream>>>(x, Wt, hb8, a_src, a_dst,
                                                bkt, gcnt, cnt, ell, ovfc, ovf, N_NODES);
  k_gat<<<(N_NODES + 3) / 4, 256, 0, stream>>>(hb8, a_src, a_dst, cnt, ell, ovfc, ovf, x, bias, gamma, beta, out, N_NODES);
}

// Round 14
// 66.629 us; speedup vs baseline: 1.1577x; 1.0058x over previous
//
#include <hip/hip_runtime.h>
#include <hip/hip_fp8.h>

#define N_NODES 50000
#define N_EDGES 800000
#define D_FEAT 128
#define HEADS 8
#define HEAD_DIM 16
#define ELL_CAP 64
#define NBKT 196            // dst>>8 in [0,196)
#define BKT_CAP 5120        // mean 4096, sigma ~64 -> +16 sigma
#define OVF_CAP 65536
#define NB_COLS 144         // 128 h-cols + 8 a_src + 8 a_dst
#define PREP_BLKS 72        // 144*128/256
#define NGEMM ((N_NODES + 63) / 64)   // 782

typedef __attribute__((ext_vector_type(8))) short bf16x8;
typedef __attribute__((ext_vector_type(4))) float f32x4;

static __device__ __forceinline__ ushort f2bf(float f) {
  uint u = __float_as_uint(f);
  u += 0x7fffu + ((u >> 16) & 1u);    // RNE
  return (ushort)(u >> 16);
}

// fp8 e4m3 (OCP on gfx950) pack/unpack via HIP types (HW cvt)
static __device__ __forceinline__ ushort pack_fp8x2(float v0, float v1) {
  __hip_fp8x2_e4m3 p(float2{v0, v1});
  return *reinterpret_cast<ushort*>(&p);
}
static __device__ __forceinline__ float2 unpack_fp8x2(ushort raw) {
  __hip_fp8x2_e4m3 p;
  *reinterpret_cast<ushort*>(&p) = raw;
  return static_cast<float2>(p);
}

static constexpr size_t alignup(size_t v) { return (v + 255) & ~255ull; }
// ---------------- workspace layout (bytes) ----------------
static constexpr size_t OFF_HB   = 0;                                           // [N,128] fp8
static constexpr size_t OFF_ASRC = alignup(OFF_HB + (size_t)N_NODES * 128);     // [N,8] f32
static constexpr size_t OFF_ADST = alignup(OFF_ASRC + (size_t)N_NODES * 8 * 4); // [N,8] f32
static constexpr size_t OFF_CNT  = alignup(OFF_ADST + (size_t)N_NODES * 8 * 4); // [N] i32
static constexpr size_t OFF_GCNT = alignup(OFF_CNT + (size_t)N_NODES * 4);      // [NBKT] i32
static constexpr size_t OFF_OVFC = OFF_GCNT + (size_t)NBKT * 4;                 // [1] i32 (contig w/ gcnt)
static constexpr size_t OFF_ELL  = alignup(OFF_OVFC + 4);                       // [N*64] u16
static constexpr size_t OFF_BKT  = alignup(OFF_ELL + (size_t)N_NODES * ELL_CAP * 2); // [NBKT*BKT_CAP] u32
static constexpr size_t OFF_OVF  = alignup(OFF_BKT + (size_t)NBKT * BKT_CAP * 4);    // [OVF_CAP] int2
static constexpr size_t OFF_WT   = alignup(OFF_OVF + (size_t)OVF_CAP * 8);      // [144*128] bf16 swizzled

// ---------------- prep: build Wt (swizzled bf16, 144 cols) + zero counters ---
__global__ __launch_bounds__(256) void k_prep(const float* __restrict__ W,
                                              const float* __restrict__ att_src,
                                              const float* __restrict__ att_dst,
                                              char* __restrict__ Wt,
                                              int* __restrict__ gcnt) {
  if (blockIdx.x == 0 && threadIdx.x <= NBKT) gcnt[threadIdx.x] = 0;  // gcnt + ovfc
  int t = blockIdx.x * 256 + threadIdx.x;   // 0..18431
  int n = t >> 7, k = t & 127;
  float v;
  if (n < 128) {
    v = W[k * 128 + n];
  } else {
    int j = n - 128, jj = j & 7;
    const float* att = (j < 8) ? att_src : att_dst;
    v = 0.f;
#pragma unroll
    for (int c = 0; c < 16; ++c) v += W[k * 128 + jj * 16 + c] * att[jj * 16 + c];
  }
  int off = (n * 256 + k * 2) ^ ((n & 7) << 4);
  *(ushort*)(Wt + off) = f2bf(v);
}

// ---------------- mega-kernel: blocks [0,NGEMM)=MFMA GEMM, rest = edge bin ---
__global__ __launch_bounds__(256) void k_gemmbin(const float* __restrict__ x,
                                                 const char* __restrict__ Wt,
                                                 ushort* __restrict__ hb8,
                                                 float* __restrict__ a_src,
                                                 float* __restrict__ a_dst,
                                                 const int* __restrict__ src,
                                                 const int* __restrict__ dst,
                                                 int* __restrict__ gcnt,
                                                 uint* __restrict__ bkt,
                                                 int* __restrict__ ovfc,
                                                 int2* __restrict__ ovf,
                                                 int N, int E) {
  __shared__ union SM {
    ushort wl[NB_COLS * 128];                       // 36 KB (gemm branch)
    struct { int hist[NBKT]; int base[NBKT]; } h;   // 1.6 KB (bin branch)
  } sm;
  const int tid = threadIdx.x;

  if (blockIdx.x < NGEMM) {
    // ---------------- GEMM branch ----------------
    const uint4* Wg4 = (const uint4*)Wt;
    uint4* Wl4 = (uint4*)sm.wl;
#pragma unroll
    for (int i = 0; i < 9; ++i) Wl4[tid + i * 256] = Wg4[tid + i * 256];
    __syncthreads();

    const int w = tid >> 6, l = tid & 63;
    const int R = blockIdx.x * 64 + w * 16;
    const int m = l & 15, kg = l >> 4;
    const char* Wlb = (const char*)sm.wl;

    f32x4 acc[9];
#pragma unroll
    for (int j = 0; j < 9; ++j) acc[j] = (f32x4){0.f, 0.f, 0.f, 0.f};

    const int row = R + m;
    const bool valid = row < N;
    const float4* xr = (const float4*)(x + (size_t)(valid ? row : 0) * 128);

#pragma unroll
    for (int kt = 0; kt < 4; ++kt) {
      const int k0 = kt * 32 + kg * 8;
      float4 xa = valid ? xr[k0 >> 2] : make_float4(0.f, 0.f, 0.f, 0.f);
      float4 xb = valid ? xr[(k0 >> 2) + 1] : make_float4(0.f, 0.f, 0.f, 0.f);
      bf16x8 a;
      a[0] = (short)f2bf(xa.x); a[1] = (short)f2bf(xa.y);
      a[2] = (short)f2bf(xa.z); a[3] = (short)f2bf(xa.w);
      a[4] = (short)f2bf(xb.x); a[5] = (short)f2bf(xb.y);
      a[6] = (short)f2bf(xb.z); a[7] = (short)f2bf(xb.w);
#pragma unroll
      for (int j = 0; j < 9; ++j) {
        int n = j * 16 + m;
        int off = (n * 256 + k0 * 2) ^ ((n & 7) << 4);
        bf16x8 b = *(const bf16x8*)(Wlb + off);
        acc[j] = __builtin_amdgcn_mfma_f32_16x16x32_bf16(a, b, acc[j], 0, 0, 0);
      }
    }
    // C layout: col = j*16 + m, row = R + kg*4 + r.
    // fp8 pack: even-m lane packs (own col, col+1 from lane m^1) -> ushort.
#pragma unroll
    for (int j = 0; j < 8; ++j) {
#pragma unroll
      for (int r = 0; r < 4; ++r) {
        float v0 = acc[j][r];
        float v1 = __shfl_xor(v0, 1);
        int rr = R + kg * 4 + r;
        if (!(m & 1) && rr < N)
          hb8[(size_t)rr * 64 + j * 8 + (m >> 1)] = pack_fp8x2(v0, v1);
      }
    }
#pragma unroll
    for (int r = 0; r < 4; ++r) {
      int rr = R + kg * 4 + r;
      if (rr < N) {
        if (m < 8) a_src[rr * 8 + m] = acc[8][r];
        else       a_dst[rr * 8 + (m - 8)] = acc[8][r];
      }
    }
    return;
  }

  // ---------------- edge-bin branch ----------------
  const int t = tid;
  const int e0 = (blockIdx.x - NGEMM) * 4096;
  for (int i = t; i < NBKT; i += 256) sm.h.hist[i] = 0;
  __syncthreads();

  uint pk[16];
  int bk[16];
#pragma unroll
  for (int j = 0; j < 4; ++j) {
    int e = e0 + j * 1024 + t * 4;
    if (e < E) {                       // E%4==0: quad fully valid
      int4 d4 = *(const int4*)(dst + e);
      int4 s4 = *(const int4*)(src + e);
      bk[j * 4 + 0] = d4.x >> 8; pk[j * 4 + 0] = ((uint)(d4.x & 255) << 16) | (uint)s4.x;
      bk[j * 4 + 1] = d4.y >> 8; pk[j * 4 + 1] = ((uint)(d4.y & 255) << 16) | (uint)s4.y;
      bk[j * 4 + 2] = d4.z >> 8; pk[j * 4 + 2] = ((uint)(d4.z & 255) << 16) | (uint)s4.z;
      bk[j * 4 + 3] = d4.w >> 8; pk[j * 4 + 3] = ((uint)(d4.w & 255) << 16) | (uint)s4.w;
      atomicAdd(&sm.h.hist[bk[j * 4 + 0]], 1);
      atomicAdd(&sm.h.hist[bk[j * 4 + 1]], 1);
      atomicAdd(&sm.h.hist[bk[j * 4 + 2]], 1);
      atomicAdd(&sm.h.hist[bk[j * 4 + 3]], 1);
    } else {
      bk[j * 4 + 0] = -1; bk[j * 4 + 1] = -1; bk[j * 4 + 2] = -1; bk[j * 4 + 3] = -1;
      pk[j * 4 + 0] = 0;  pk[j * 4 + 1] = 0;  pk[j * 4 + 2] = 0;  pk[j * 4 + 3] = 0;
    }
  }
  __syncthreads();
  for (int i = t; i < NBKT; i += 256) {
    sm.h.base[i] = atomicAdd(&gcnt[i], sm.h.hist[i]);
    sm.h.hist[i] = 0;
  }
  __syncthreads();
#pragma unroll
  for (int j = 0; j < 16; ++j) {
    if (bk[j] >= 0) {
      int pos = atomicAdd(&sm.h.hist[bk[j]], 1);
      int gp = sm.h.base[bk[j]] + pos;
      if (gp < BKT_CAP) {
        bkt[(size_t)bk[j] * BKT_CAP + gp] = pk[j];
      } else {
        int q = atomicAdd(ovfc, 1);
        if (q < OVF_CAP) ovf[q] = make_int2((bk[j] << 8) | (int)(pk[j] >> 16), (int)(pk[j] & 0xffffu));
      }
    }
  }
}

// ---------------- pass 2: per-bucket ELL build in LDS, coalesced writeout ----
__global__ __launch_bounds__(256) void k_build(const uint* __restrict__ bkt,
                                               const int* __restrict__ gcnt,
                                               int* __restrict__ cnt,
                                               ushort* __restrict__ ell,
                                               int* __restrict__ ovfc,
                                               int2* __restrict__ ovf) {
  __shared__ ushort lell[256 * ELL_CAP];   // 32KB
  __shared__ int lcnt[256];
  const int b = blockIdx.x;
  const int t = threadIdx.x;
  lcnt[t] = 0;
  __syncthreads();

  const int nb = min(gcnt[b], BKT_CAP);
  for (int i = t; i < nb; i += 256) {
    uint pk = bkt[(size_t)b * BKT_CAP + i];
    int dl = (int)(pk >> 16);
    int pos = atomicAdd(&lcnt[dl], 1);
    if (pos < ELL_CAP) {
      lell[dl * ELL_CAP + pos] = (ushort)(pk & 0xffffu);
    } else {
      int q = atomicAdd(ovfc, 1);
      if (q < OVF_CAP) ovf[q] = make_int2((b << 8) | dl, (int)(pk & 0xffffu));
    }
  }
  __syncthreads();

  const int n0 = b << 8;
  if (n0 + t < N_NODES) cnt[n0 + t] = lcnt[t];
  const uint4* l4 = (const uint4*)lell;
  uint4* g4 = (uint4*)(ell + (size_t)n0 * ELL_CAP);
  for (int i = t; i < 2048; i += 256) {       // 256 nodes * 128B = 32KB
    if (n0 + (i >> 3) < N_NODES) g4[i] = l4[i];
  }
}

// ---------------- gather + softmax aggregate + residual + LN ----------------
static __device__ __forceinline__ uint sel_idx(uint4 qi, uint kp) {
  uint w01 = (kp & 2) ? qi.y : qi.x;
  uint w23 = (kp & 2) ? qi.w : qi.z;
  uint word = (kp & 4) ? w23 : w01;
  return (kp & 1) ? (word >> 16) : (word & 0xffffu);
}

// 16 edges, no clamp (deg >= e+16)
static __device__ __forceinline__ void gat_block16(const ushort* __restrict__ hu8,
                                                   const float* __restrict__ a_src,
                                                   const ushort* __restrict__ row,
                                                   int e, uint hd, uint lane,
                                                   float adst, float& acc0, float& acc1,
                                                   float& den) {
  uint4 qa = *(const uint4*)(row + e);
  uint4 qb = *(const uint4*)(row + e + 8);
  uint s[16];
  s[0] = qa.x & 0xffffu; s[1] = qa.x >> 16; s[2] = qa.y & 0xffffu; s[3] = qa.y >> 16;
  s[4] = qa.z & 0xffffu; s[5] = qa.z >> 16; s[6] = qa.w & 0xffffu; s[7] = qa.w >> 16;
  s[8]  = qb.x & 0xffffu; s[9]  = qb.x >> 16; s[10] = qb.y & 0xffffu; s[11] = qb.y >> 16;
  s[12] = qb.z & 0xffffu; s[13] = qb.z >> 16; s[14] = qb.w & 0xffffu; s[15] = qb.w >> 16;

  const uint kp = lane & 7;
  uint sva = sel_idx(qa, kp);
  uint svb = sel_idx(qb, kp);
  float Aa = a_src[sva * 8u + hd];
  float Ab = a_src[svb * 8u + hd];

  ushort u[16];
#pragma unroll
  for (int k = 0; k < 16; ++k) u[k] = hu8[(s[k] << 6) | lane];

  float aa = Aa + adst; aa = aa > 0.f ? aa : 0.2f * aa;
  float ab = Ab + adst; ab = ab > 0.f ? ab : 0.2f * ab;
  float pma = __expf(aa);
  float pmb = __expf(ab);

  const int pbase = (int)(lane & 0x38u);    // hd*8
#pragma unroll
  for (int k = 0; k < 8; ++k) {
    float p = __shfl(pma, pbase | k);
    float2 hv = unpack_fp8x2(u[k]);
    acc0 = fmaf(p, hv.x, acc0);
    acc1 = fmaf(p, hv.y, acc1);
    den += p;
  }
#pragma unroll
  for (int k = 0; k < 8; ++k) {
    float p = __shfl(pmb, pbase | k);
    float2 hv = unpack_fp8x2(u[8 + k]);
    acc0 = fmaf(p, hv.x, acc0);
    acc1 = fmaf(p, hv.y, acc1);
    den += p;
  }
}

template<bool CLAMP>
static __device__ __forceinline__ void gat_block(const ushort* __restrict__ hu8,
                                                 const float* __restrict__ a_src,
                                                 const ushort* __restrict__ row,
                                                 int e, int deg, uint hd, uint lane,
                                                 float adst, float& acc0, float& acc1,
                                                 float& den) {
  uint4 qi = *(const uint4*)(row + e);      // 8 u16 indices, wave-uniform 16B
  uint s[8];
  s[0] = qi.x & 0xffffu; s[1] = qi.x >> 16;
  s[2] = qi.y & 0xffffu; s[3] = qi.y >> 16;
  s[4] = qi.z & 0xffffu; s[5] = qi.z >> 16;
  s[6] = qi.w & 0xffffu; s[7] = qi.w >> 16;

  const uint kp = lane & 7;
  uint sv = sel_idx(qi, kp);
  float a = a_src[sv * 8u + hd] + adst;
  a = a > 0.f ? a : 0.2f * a;               // LeakyReLU(0.2)
  float pm = __expf(a);
  if (CLAMP && (int)(e + kp) >= deg) pm = 0.f;

  ushort u[8];
#pragma unroll
  for (int k = 0; k < 8; ++k) {
    uint sk = s[k];
    if (CLAMP && e + k >= deg) sk = 0;      // safe gather (p already 0)
    u[k] = hu8[(sk << 6) | lane];
  }
  const int pbase = (int)(lane & 0x38u);    // hd*8
#pragma unroll
  for (int k = 0; k < 8; ++k) {
    float p = __shfl(pm, pbase | k);        // p(edge k, this lane's head)
    float2 hv = unpack_fp8x2(u[k]);
    acc0 = fmaf(p, hv.x, acc0);
    acc1 = fmaf(p, hv.y, acc1);
    den += p;
  }
}

__global__ __launch_bounds__(256) void k_gat(const ushort* __restrict__ hb8,
                                             const float* __restrict__ a_src,
                                             const float* __restrict__ a_dst,
                                             const int* __restrict__ cnt,
                                             const ushort* __restrict__ ell,
                                             const int* __restrict__ ovfc,
                                             const int2* __restrict__ ovf,
                                             const float* __restrict__ x,
                                             const float* __restrict__ bias,
                                             const float* __restrict__ gamma,
                                             const float* __restrict__ beta,
                                             float* __restrict__ out, int N) {
  const int wid = threadIdx.x >> 6;
  const uint lane = threadIdx.x & 63;
  const int n = blockIdx.x * 4 + wid;
  if (n >= N) return;
  const uint hd = lane >> 3;
  const float adst = a_dst[n * 8 + hd];
  const int degt = cnt[n];
  const int deg = degt < ELL_CAP ? degt : ELL_CAP;
  const ushort* row = ell + (size_t)n * ELL_CAP;

  float acc0 = 0.f, acc1 = 0.f, den = 0.f;
  int e = 0;
  for (; e + 16 <= deg; e += 16)
    gat_block16(hb8, a_src, row, e, hd, lane, adst, acc0, acc1, den);
  if (deg - e >= 8) {
    gat_block<false>(hb8, a_src, row, e, deg, hd, lane, adst, acc0, acc1, den);
    e += 8;
  }
  if (e < deg)
    gat_block<true>(hb8, a_src, row, e, deg, hd, lane, adst, acc0, acc1, den);

  {
    int novf = *ovfc;                        // ~always 0; one broadcast load
    if (novf > 0) {
      novf = novf < OVF_CAP ? novf : OVF_CAP;
      for (int q = 0; q < novf; ++q) {
        int2 pr = ovf[q];
        if (pr.x == n) {
          uint s = (uint)pr.y;
          float a = a_src[s * 8u + hd] + adst;
          a = a > 0.f ? a : 0.2f * a;
          float p = __expf(a);
          float2 hv = unpack_fp8x2(hb8[(s << 6) | lane]);
          acc0 = fmaf(p, hv.x, acc0);
          acc1 = fmaf(p, hv.y, acc1);
          den += p;
        }
      }
    }
  }
  float r = 1.0f / (den + 1e-16f);
  float2 bv = ((const float2*)bias)[lane];
  float2 xv = ((const float2*)x)[(size_t)n * 64 + lane];
  float o0 = fmaf(acc0, r, bv.x + xv.x);
  float o1 = fmaf(acc1, r, bv.y + xv.y);

  float s1 = o0 + o1;
  float s2 = o0 * o0 + o1 * o1;
#pragma unroll
  for (int off = 32; off > 0; off >>= 1) {
    s1 += __shfl_xor(s1, off);
    s2 += __shfl_xor(s2, off);
  }
  float mean = s1 * (1.0f / 128.0f);
  float var = s2 * (1.0f / 128.0f) - mean * mean;
  var = var < 0.f ? 0.f : var;
  float rstd = rsqrtf(var + 1e-5f);
  float2 gv = ((const float2*)gamma)[lane];
  float2 bt = ((const float2*)beta)[lane];
  float2 ov;
  ov.x = (o0 - mean) * rstd * gv.x + bt.x;
  ov.y = (o1 - mean) * rstd * gv.y + bt.y;
  ((float2*)out)[(size_t)n * 64 + lane] = ov;
}

// ---------------- launch ----------------
extern "C" void kernel_launch(void* const* d_in, const int* in_sizes, int n_in,
                              void* d_out, int out_size, void* d_ws, size_t ws_size,
                              hipStream_t stream) {
  const float* x       = (const float*)d_in[0];
  const int*   ei      = (const int*)d_in[1];
  const float* W       = (const float*)d_in[2];
  const float* att_src = (const float*)d_in[3];
  const float* att_dst = (const float*)d_in[4];
  const float* bias    = (const float*)d_in[5];
  const float* gamma   = (const float*)d_in[6];
  const float* beta    = (const float*)d_in[7];
  float* out = (float*)d_out;

  char* ws = (char*)d_ws;
  ushort* hb8  = (ushort*)(ws + OFF_HB);
  float* a_src = (float*)(ws + OFF_ASRC);
  float* a_dst = (float*)(ws + OFF_ADST);
  int* cnt   = (int*)(ws + OFF_CNT);
  int* gcnt  = (int*)(ws + OFF_GCNT);
  int* ovfc  = (int*)(ws + OFF_OVFC);
  ushort* ell = (ushort*)(ws + OFF_ELL);
  uint* bkt  = (uint*)(ws + OFF_BKT);
  int2* ovf  = (int2*)(ws + OFF_OVF);
  char* Wt   = ws + OFF_WT;

  const int* srcIdx = ei;
  const int* dstIdx = ei + N_EDGES;

  k_prep<<<PREP_BLKS, 256, 0, stream>>>(W, att_src, att_dst, Wt, gcnt);   // also zeros gcnt+ovfc
  k_gemmbin<<<NGEMM + NBKT, 256, 0, stream>>>(x, Wt, hb8, a_src, a_dst,
                                              srcIdx, dstIdx, gcnt, bkt, ovfc, ovf,
                                              N_NODES, N_EDGES);
  k_build<<<NBKT, 256, 0, stream>>>(bkt, gcnt, cnt, ell, ovfc, ovf);
  k_gat<<<(N_NODES + 3) / 4, 256, 0, stream>>>(hb8, a_src, a_dst, cnt, ell, ovfc, ovf, x, bias, gamma, beta, out, N_NODES);
}